// Round 11
// baseline (632.554 us; speedup 1.0000x reference)
//
// GLA fused pipeline v7.1 — v7 with StP/carry aliased into dead buffers (no workspace growth)
#include <hip/hip_runtime.h>
#include <hip/hip_bf16.h>
#include <cstdint>

typedef unsigned short u16;
typedef unsigned int u32;
typedef float f32x4 __attribute__((ext_vector_type(4)));
typedef short bf16x8 __attribute__((ext_vector_type(8)));

#define T_TOK 8192
#define HID 2048
#define NH 16
#define NKV 4
#define HD 128
#define QKVN 3072   // (16+2*4)*128
#define CHUNK 64
#define NC 128      // 8192/64
#define NSEG 8
#define SEGLEN 16   // NC/NSEG

__device__ __forceinline__ float bf2f(u16 h){
  u32 u = ((u32)h) << 16;
  return __builtin_bit_cast(float, u);
}
__device__ __forceinline__ u16 f2bf(float f){
  u32 u = __builtin_bit_cast(u32, f);
  u32 r = (u + 0x7fffu + ((u >> 16) & 1u)) >> 16;
  return (u16)r;
}
__device__ __forceinline__ u32 pack2(float a, float b){
  return (u32)f2bf(a) | ((u32)f2bf(b) << 16);
}
// async global->LDS, 16B per lane. LDS dest must be wave-uniform base + lane*16.
__device__ __forceinline__ void gl2lds16(const u16* g, u16* l){
  __builtin_amdgcn_global_load_lds(
      (const __attribute__((address_space(1))) u32*)g,
      (__attribute__((address_space(3))) u32*)l, 16, 0, 0);
}

// f32 -> bf16 bulk convert (8 elems/thread)
__global__ __launch_bounds__(256) void cvt_f2b_kernel(
    const float* __restrict__ in, u16* __restrict__ out, int n8)
{
  int i = blockIdx.x*256 + threadIdx.x;
  if (i >= n8) return;
  const float4* p = (const float4*)(in + (size_t)i*8);
  float4 a = p[0], b = p[1];
  uint4 pk;
  pk.x = pack2(a.x, a.y); pk.y = pack2(a.z, a.w);
  pk.z = pack2(b.x, b.y); pk.w = pack2(b.z, b.w);
  *(uint4*)(out + (size_t)i*8) = pk;
}

// ---------------------------------------------------------------------------
// gemm_v2 (r4, refcheck-passed): BM=BN=256, BK=64, 512 threads, 4 phases x
// 16 MFMA per K-tile, 128 KB LDS dbuf, counted vmcnt(2), 0-conflict swizzle,
// bn-fastest XCD chunk map. Used ONLY where grid == 256 (one exact round).
// ---------------------------------------------------------------------------
#define BM 256
#define BN 256
#define BKV2 64
#define ABUF (BM*BKV2)        // u16 elements (32 KB)
#define BBUF (BN*BKV2)        // u16 elements (32 KB)
#define BUFU (ABUF + BBUF)    // 32768 u16 = 64 KB

__device__ __forceinline__ int swz(int o){ return o ^ (((o >> 7) & 7) << 4); }

__device__ __forceinline__ void stage16(const u16* g, int ldg, u16* l, int o){
  int p = o ^ (((o >> 7) & 7) << 4);   // logical byte offset (involution)
  gl2lds16(g + (size_t)(p >> 7) * ldg + ((p >> 1) & 63), l + (o >> 1));
}

__device__ __forceinline__ void stage_half(const u16* g, int ldg, u16* lregion,
                                           int half, int tid){
  stage16(g, ldg, lregion, (half*1024 + tid)*16);
  stage16(g, ldg, lregion, (half*1024 + 512 + tid)*16);
}

template<typename YT>
__global__ __launch_bounds__(512, 2) void gemm_v2(
    const u16* __restrict__ X, const u16* __restrict__ Wt,
    const float* __restrict__ bias, const float* __restrict__ ebuf,
    const float* __restrict__ rbuf, YT* __restrict__ Y,
    int M, int N, int K, int mode)
{
  __shared__ u16 lds[2 * BUFU];        // 128 KB
  const int tid  = threadIdx.x;
  const int lane = tid & 63;
  const int wave = tid >> 6;           // 0..7
  const int wm = wave >> 2;
  const int wn = wave & 3;
  const int ml = lane & 15, quad = lane >> 4;

  const int nwg = gridDim.x;           // divisible by 8
  const int chunk = nwg >> 3;
  const int lg = (blockIdx.x & 7) * chunk + (blockIdx.x >> 3);
  const int NBt = N >> 8;              // N / 256
  const int bm0 = (lg / NBt) * BM;
  const int bn0 = (lg % NBt) * BN;

  const u16* gA = X  + (size_t)bm0 * K;
  const u16* gB = Wt + (size_t)bn0 * K;

  f32x4 acc[8][4];
  #pragma unroll
  for (int i = 0; i < 8; i++)
    #pragma unroll
    for (int j = 0; j < 4; j++) acc[i][j] = f32x4{0.f, 0.f, 0.f, 0.f};

  const int NT = K >> 6;               // K / BKV2

  auto ldfrag = [&](const u16* base, int row, int kk)->bf16x8{
    return *(const bf16x8*)((const char*)base + swz(row*128 + kk*64 + quad*16));
  };

  // ---- prologue: stage tile 0 as B0,B1,A0,A1 (8 loads/thread) ----
  {
    u16* La0 = lds;
    u16* Lb0 = lds + ABUF;
    stage_half(gB, K, Lb0, 0, tid);
    stage_half(gB, K, Lb0, 1, tid);
    stage_half(gA, K, La0, 0, tid);
    stage_half(gA, K, La0, 1, tid);
  }
  asm volatile("s_waitcnt vmcnt(2)" ::: "memory");   // B0,B1,A0 landed
  __builtin_amdgcn_s_barrier();

  // ---- main loop: 4 phases per K-tile ----
  for (int t = 0; t < NT; ++t){
    u16* La = lds + (t & 1) * BUFU;
    u16* Lb = La + ABUF;
    u16* Na = lds + ((t + 1) & 1) * BUFU;
    u16* Nb = Na + ABUF;
    const u16* ga = gA + (t + 1) * BKV2;
    const u16* gb = gB + (t + 1) * BKV2;
    const bool st = (t + 1 < NT);

    #pragma unroll
    for (int kk = 0; kk < 2; ++kk){
      bf16x8 af[4], bfr[4];
      // ---- phase (kk, rh=0) ----
      #pragma unroll
      for (int j = 0; j < 4; ++j) bfr[j] = ldfrag(Lb, wn*64 + j*16 + ml, kk);
      #pragma unroll
      for (int i = 0; i < 4; ++i) af[i] = ldfrag(La, wm*64 + i*16 + ml, kk);
      if (st){
        if (kk == 0) stage_half(gb, K, Nb, 0, tid);   // B0'
        else         stage_half(ga, K, Na, 0, tid);   // A0'
      }
      __builtin_amdgcn_sched_barrier(0);
      __builtin_amdgcn_s_barrier();
      asm volatile("s_waitcnt lgkmcnt(0)" ::: "memory");
      __builtin_amdgcn_sched_barrier(0);
      __builtin_amdgcn_s_setprio(1);
      #pragma unroll
      for (int i = 0; i < 4; ++i)
        #pragma unroll
        for (int j = 0; j < 4; ++j)
          acc[i][j] = __builtin_amdgcn_mfma_f32_16x16x32_bf16(af[i], bfr[j], acc[i][j], 0, 0, 0);
      __builtin_amdgcn_s_setprio(0);
      if (kk == 0){
        if (st) asm volatile("s_waitcnt vmcnt(2)" ::: "memory");
        else    asm volatile("s_waitcnt vmcnt(0)" ::: "memory");
      }
      __builtin_amdgcn_s_barrier();

      // ---- phase (kk, rh=1) ----
      #pragma unroll
      for (int i = 0; i < 4; ++i) af[i] = ldfrag(La, 128 + wm*64 + i*16 + ml, kk);
      if (st){
        if (kk == 0) stage_half(gb, K, Nb, 1, tid);   // B1'
        else         stage_half(ga, K, Na, 1, tid);   // A1'
      }
      __builtin_amdgcn_sched_barrier(0);
      __builtin_amdgcn_s_barrier();
      asm volatile("s_waitcnt lgkmcnt(0)" ::: "memory");
      __builtin_amdgcn_sched_barrier(0);
      __builtin_amdgcn_s_setprio(1);
      #pragma unroll
      for (int i = 0; i < 4; ++i)
        #pragma unroll
        for (int j = 0; j < 4; ++j)
          acc[4+i][j] = __builtin_amdgcn_mfma_f32_16x16x32_bf16(af[i], bfr[j], acc[4+i][j], 0, 0, 0);
      __builtin_amdgcn_s_setprio(0);
      if (kk == 1 && st)
        asm volatile("s_waitcnt vmcnt(2)" ::: "memory");
      __builtin_amdgcn_s_barrier();
    }
  }

  // ---- epilogue ----
  #pragma unroll
  for (int rh = 0; rh < 2; rh++){
    #pragma unroll
    for (int i = 0; i < 4; i++){
      int row = bm0 + rh*128 + wm*64 + i*16 + quad*4;
      #pragma unroll
      for (int j = 0; j < 4; j++){
        int col = bn0 + wn*64 + j*16 + ml;
        float bv = 0.f;
        if (mode == 1) bv = bias[col];
        #pragma unroll
        for (int rr2 = 0; rr2 < 4; rr2++){
          float v = acc[rh*4+i][j][rr2] + bv;
          if (mode == 1){
            int token = row + rr2;
            int cc = token >> 6, tt = token & 63, ii = col & 127;
            if (col < 2048){
              v = fmaxf(v, 0.f) * 0.08838834764831845f;
              v *= ebuf[(((size_t)cc*4 + (col>>9))*64 + tt)*128 + ii];
            } else if (col < 2560){
              v = fmaxf(v, 0.f);
              v *= rbuf[(((size_t)cc*4 + ((col-2048)>>7))*64 + tt)*128 + ii];
            }
          }
          if (sizeof(YT) == 2) Y[(size_t)(row+rr2)*N + col] = (YT)f2bf(v);
          else                 Y[(size_t)(row+rr2)*N + col] = (YT)v;
        }
      }
    }
  }
}

// ---------------------------------------------------------------------------
// gemm_v4s (r9): m97 128^2 + 3-buffer ring + counted vmcnt + XCD map +
// both-sides XOR swizzle (0 bank conflicts, verified r9).
// ---------------------------------------------------------------------------
template<typename YT>
__global__ __launch_bounds__(256) void gemm_v4s(
    const u16* __restrict__ X, const u16* __restrict__ Wt,
    const float* __restrict__ bias, const float* __restrict__ ebuf,
    const float* __restrict__ rbuf, YT* __restrict__ Y,
    int M, int N, int K, int mode)
{
  __shared__ u16 lds[3 * 8192];        // 48 KB
  const int tid = threadIdx.x;
  const int lane = tid & 63;
  const int wave = tid >> 6;
  const int wm = wave >> 1, wn = wave & 1;

  const int nwg = gridDim.x;           // divisible by 8
  const int chunk = nwg >> 3;
  const int lg = (blockIdx.x & 7) * chunk + (blockIdx.x >> 3);
  const int NBt = N >> 7;              // N / 128
  const int bm0 = (lg / NBt) * 128;
  const int bn0 = (lg % NBt) * 128;

  f32x4 acc[4][4];
  #pragma unroll
  for (int i=0;i<4;i++)
    #pragma unroll
    for (int j=0;j<4;j++) acc[i][j] = f32x4{0.f,0.f,0.f,0.f};

  const int row0 = tid >> 2, part8 = (tid & 3) * 8;
  const int mrow = lane & 15, q16b = (lane >> 4) << 4;   // byte col of frag
  const u16* xb = X  + (size_t)bm0 * K;
  const u16* wb = Wt + (size_t)bn0 * K;

  const int NT = K >> 5;               // K / 32 (NT >= 2)

  auto scol = [&](int rr)->int{
    return (((tid & 3) * 16) ^ (((rr >> 1) & 3) << 4)) >> 1;
  };

  #pragma unroll
  for (int tt = 0; tt < 2; ++tt){
    u16* As = lds + tt * 8192;
    u16* Bs = As + 4096;
    int k0 = tt * 32;
    #pragma unroll
    for (int j=0;j<2;j++){
      int rr = j*64 + row0;
      gl2lds16(xb + (size_t)rr*K + k0 + scol(rr), As + rr*32 + part8);
      gl2lds16(wb + (size_t)rr*K + k0 + scol(rr), Bs + rr*32 + part8);
    }
  }
  asm volatile("s_waitcnt vmcnt(4)" ::: "memory");   // tile 0 landed
  __builtin_amdgcn_s_barrier();

  for (int t = 0; t < NT; ++t){
    u16* As = lds + (t % 3) * 8192;
    u16* Bs = As + 4096;
    if (t + 2 < NT){
      u16* Ns = lds + ((t + 2) % 3) * 8192;
      int k0 = (t + 2) * 32;
      #pragma unroll
      for (int j=0;j<2;j++){
        int rr = j*64 + row0;
        gl2lds16(xb + (size_t)rr*K + k0 + scol(rr), Ns + rr*32 + part8);
        gl2lds16(wb + (size_t)rr*K + k0 + scol(rr), Ns + 4096 + rr*32 + part8);
      }
    }
    bf16x8 af[4], bfr[4];
    #pragma unroll
    for (int i=0;i<4;i++){
      int ra = wm*64 + i*16 + mrow;
      int rb = wn*64 + i*16 + mrow;
      af[i]  = *(const bf16x8*)((const char*)As + ra*64 + (q16b ^ (((ra>>1)&3)<<4)));
      bfr[i] = *(const bf16x8*)((const char*)Bs + rb*64 + (q16b ^ (((rb>>1)&3)<<4)));
    }
    #pragma unroll
    for (int i=0;i<4;i++)
      #pragma unroll
      for (int j=0;j<4;j++)
        acc[i][j] = __builtin_amdgcn_mfma_f32_16x16x32_bf16(af[i], bfr[j], acc[i][j], 0, 0, 0);
    if (t + 2 < NT)      asm volatile("s_waitcnt vmcnt(4)" ::: "memory");
    else if (t + 1 < NT) asm volatile("s_waitcnt vmcnt(0)" ::: "memory");
    __builtin_amdgcn_s_barrier();
  }

  #pragma unroll
  for (int i=0;i<4;i++){
    int row = bm0 + wm*64 + i*16 + (lane>>4)*4;
    #pragma unroll
    for (int j=0;j<4;j++){
      int col = bn0 + wn*64 + j*16 + (lane&15);
      float bv = 0.f;
      if (mode == 1) bv = bias[col];
      #pragma unroll
      for (int rr2=0;rr2<4;rr2++){
        float v = acc[i][j][rr2] + bv;
        if (mode == 1){
          int token = row + rr2;
          int cc = token >> 6, tt = token & 63, ii = col & 127;
          if (col < 2048){
            v = fmaxf(v, 0.f) * 0.08838834764831845f;
            v *= ebuf[(((size_t)cc*4 + (col>>9))*64 + tt)*128 + ii];
          } else if (col < 2560){
            v = fmaxf(v, 0.f);
            v *= rbuf[(((size_t)cc*4 + ((col-2048)>>7))*64 + tt)*128 + ii];
          }
        }
        if (sizeof(YT) == 2) Y[(size_t)(row+rr2)*N + col] = (YT)f2bf(v);
        else                 Y[(size_t)(row+rr2)*N + col] = (YT)v;
      }
    }
  }
}

// in[R,C] (f32) -> out[C,R] (bf16), 32x32 LDS tiles
__global__ __launch_bounds__(256) void transpose_f2b(
    const float* __restrict__ in, u16* __restrict__ out, int R, int C)
{
  __shared__ float tile[32][33];
  int c0 = blockIdx.x*32, r0 = blockIdx.y*32;
  int tx = threadIdx.x & 31, ty = threadIdx.x >> 5;
  #pragma unroll
  for (int p=0;p<4;p++) tile[ty + p*8][tx] = in[(size_t)(r0 + ty + p*8)*C + c0 + tx];
  __syncthreads();
  #pragma unroll
  for (int p=0;p<4;p++) out[(size_t)(c0 + ty + p*8)*R + r0 + tx] = f2bf(tile[tx][ty + p*8]);
}

// gate low-rank stage 1 (vectorized bf16x8 loads): tmp[T,16] = hs @ w0
__global__ __launch_bounds__(256) void gk1_kernel(
    const u16* __restrict__ hsb, const float* __restrict__ w0, float* __restrict__ tmp)
{
  int row = blockIdx.x*4 + (threadIdx.x >> 6);
  int lane = threadIdx.x & 63;
  float acc[16];
  #pragma unroll
  for (int n=0;n<16;n++) acc[n]=0.f;
  #pragma unroll
  for (int it=0; it<4; ++it){
    int k = it*512 + lane*8;
    uint4 pk = *(const uint4*)(hsb + (size_t)row*HID + k);
    const u16* hv = (const u16*)&pk;
    #pragma unroll
    for (int e=0;e<8;e++){
      float h = bf2f(hv[e]);
      const float* wr = w0 + (size_t)(k+e)*16;
      #pragma unroll
      for (int q=0;q<4;q++){
        float4 wv = *(const float4*)(wr + q*4);
        acc[q*4+0] += h*wv.x; acc[q*4+1] += h*wv.y;
        acc[q*4+2] += h*wv.z; acc[q*4+3] += h*wv.w;
      }
    }
  }
  #pragma unroll
  for (int n=0;n<16;n++){
    #pragma unroll
    for (int off=32; off>0; off>>=1)
      acc[n] += __shfl_down(acc[n], off);
  }
  if (lane == 0){
    #pragma unroll
    for (int n=0;n<16;n++) tmp[(size_t)row*16 + n] = acc[n];
  }
}

// gate stage 2: g[T,512] = logsigmoid(tmp @ w1 + b1) / 16
__global__ __launch_bounds__(256) void gk2_kernel(
    const float* __restrict__ tmp, const float* __restrict__ w1,
    const float* __restrict__ b1, float* __restrict__ g)
{
  int id = blockIdx.x*256 + threadIdx.x;
  int rrow = id >> 9, n = id & 511;
  float a = b1[n];
  #pragma unroll
  for (int k=0;k<16;k++)
    a += tmp[(size_t)rrow*16 + k] * w1[k*512 + n];
  float ls = fminf(a, 0.f) - log1pf(__expf(-fabsf(a)));
  g[id] = ls * 0.0625f;
}

// Per (c,h): cumsum gates -> ebuf=e^b, rbuf=e^-b (f32), expB=e^{b_63}
__global__ __launch_bounds__(256) void decay_kernel(
    const float* __restrict__ g, float* __restrict__ ebuf,
    float* __restrict__ rbuf, float* __restrict__ expB)
{
  __shared__ float bL[CHUNK*HD];
  const int c = blockIdx.x, h = blockIdx.y, tid = threadIdx.x;
  for (int off = tid; off < CHUNK*HD; off += 256){
    int t = off >> 7, i = off & 127;
    bL[off] = g[(size_t)(c*CHUNK + t)*512 + h*HD + i];
  }
  __syncthreads();
  if (tid < HD){
    float run = 0.f;
    for (int t=0;t<CHUNK;t++){ run += bL[t*HD + tid]; bL[t*HD + tid] = run; }
    expB[(size_t)(c*NKV + h)*HD + tid] = __expf(run);
  }
  __syncthreads();
  size_t base = (size_t)(c*NKV + h)*CHUNK*HD;
  for (int off = tid; off < CHUNK*HD; off += 256){
    float b = bL[off];
    ebuf[base + off] = __expf(b);
    rbuf[base + off] = __expf(-b);
  }
}

// Per (c,h): Kt[j][i] = expB[i] * sum_t v[t][j]*kd[t][i] (bf16),
//            Vt[j][s] = v[s][j] (bf16)
__global__ __launch_bounds__(256) void chunk_stats2_kernel(
    const u16* __restrict__ qkv, const float* __restrict__ expB,
    u16* __restrict__ Kt, u16* __restrict__ Vt)
{
  __shared__ u16 kL[CHUNK*HD];
  __shared__ u16 vL[CHUNK*HD];
  const int c = blockIdx.x, h = blockIdx.y, tid = threadIdx.x;
  #pragma unroll
  for (int it=0; it<4; it++){
    int u = it*256 + tid;              // 0..1023, one uint4 each of kL,vL
    int t = u >> 4, p = (u & 15)*8;
    size_t tok = (size_t)(c*CHUNK + t);
    *(uint4*)(kL + t*HD + p) = *(const uint4*)(qkv + tok*QKVN + 2048 + h*HD + p);
    *(uint4*)(vL + t*HD + p) = *(const uint4*)(qkv + tok*QKVN + 2560 + h*HD + p);
  }
  __syncthreads();
  // Vt emit
  {
    int j = tid >> 1, sh = (tid & 1)*32;
    u16* dst = Vt + ((size_t)(c*NKV + h)*HD + j)*CHUNK + sh;
    #pragma unroll
    for (int s2=0; s2<16; s2++){
      u32 a = (u32)vL[(sh + 2*s2)*HD + j] | ((u32)vL[(sh + 2*s2 + 1)*HD + j] << 16);
      *(u32*)(dst + 2*s2) = a;
    }
  }
  // Kt
  int jj = tid >> 1, ih = (tid & 1)*64;
  float acc[64];
  #pragma unroll
  for (int z=0;z<64;z++) acc[z]=0.f;
  for (int t=0;t<CHUNK;t++){
    float vj = bf2f(vL[t*HD + jj]);
    const u32* kp = (const u32*)(kL + t*HD + ih);
    #pragma unroll
    for (int z2=0; z2<32; z2++){
      u32 kw = kp[z2];
      acc[2*z2]   += vj * bf2f((u16)(kw & 0xffffu));
      acc[2*z2+1] += vj * bf2f((u16)(kw >> 16));
    }
  }
  u16* kout = Kt + ((size_t)(c*NKV + h)*HD + jj)*HD + ih;
  const float* eB = expB + (size_t)(c*NKV + h)*HD + ih;
  #pragma unroll
  for (int z2=0; z2<32; z2++)
    *(u32*)(kout + 2*z2) = pack2(acc[2*z2]*eB[2*z2], acc[2*z2+1]*eB[2*z2+1]);
}

// ---------------------------------------------------------------------------
// Segmented state scan (replaces serial state_scan2, which ran at 4 waves/CU
// with a 128-deep dependent-load chain). Linear recurrence superposition:
//   state(cc) = StP(cc) + [prod e over seg-start..cc-1] * S_start(seg)
// Pass A: per (s,elem) within-segment scan from 0 -> StP (f32) + carry.
// Pass C: combine carries (A_s from L2-resident expB) and emit St (bf16,
// single rounding). Both passes: 524288 threads = 32 waves/CU.
// StP aliases ebuf||rbuf (32 MB, dead after qkv GEMM); carry aliases g
// (dead after decay) -> no workspace growth vs the r9-passing layout.
// ---------------------------------------------------------------------------
__global__ __launch_bounds__(256) void scan_a_kernel(
    const u16* __restrict__ Kt, const float* __restrict__ expB,
    float* __restrict__ StP, float* __restrict__ carry)
{
  size_t u = (size_t)blockIdx.x*256 + threadIdx.x;   // (s,h,j,i), i fastest
  int i = u & 127;
  int h = (u >> 14) & 3;
  int s = (int)(u >> 16);
  size_t base = (u & 65535);           // elem index ((h*HD+j)*HD+i)
  float S = 0.f;
  int c0 = s * SEGLEN;
  #pragma unroll
  for (int q = 0; q < SEGLEN; ++q){
    int cc = c0 + q;
    size_t off = (size_t)cc*(NKV*HD*HD) + base;
    StP[off] = S;
    S = expB[((size_t)cc*NKV + h)*HD + i] * S + bf2f(Kt[off]);
  }
  carry[u] = S;
}

__global__ __launch_bounds__(256) void scan_c_kernel(
    const float* __restrict__ StP, const float* __restrict__ expB,
    const float* __restrict__ carry, u16* __restrict__ St)
{
  size_t u = (size_t)blockIdx.x*256 + threadIdx.x;
  int i = u & 127;
  int h = (u >> 14) & 3;
  int s = (int)(u >> 16);                 // uniform per block (256 | 65536)
  size_t elem = u & 65535;
  // combine carries of segments 0..s-1: S_start = B_sp + A_sp * S_start
  float Sst = 0.f;
  for (int sp = 0; sp < s; ++sp){
    float A = 1.f;
    int c0 = sp * SEGLEN;
    #pragma unroll
    for (int q = 0; q < SEGLEN; ++q)
      A *= expB[((size_t)(c0+q)*NKV + h)*HD + i];
    Sst = carry[(size_t)sp*65536 + elem] + A * Sst;
  }
  int c0 = s * SEGLEN;
  float P = 1.f;
  #pragma unroll
  for (int q = 0; q < SEGLEN; ++q){
    int cc = c0 + q;
    size_t off = (size_t)cc*(NKV*HD*HD) + elem;
    St[off] = f2bf(StP[off] + P * Sst);
    P *= expB[((size_t)cc*NKV + h)*HD + i];
  }
}

// Fused intra-chunk attention per (c, qh):
//   A = tril(qe @ kd^T)  [64x64]  -> P (LDS, bf16)
//   o = P @ Vt + qe @ St [64x128], RMSNorm rows, -> obuf bf16
__global__ __launch_bounds__(256) void attn_fused_kernel(
    const u16* __restrict__ qkv, const u16* __restrict__ St,
    const u16* __restrict__ Vt, const float* __restrict__ gw,
    u16* __restrict__ obuf)
{
  __shared__ u16 qe[64*136];
  __shared__ u16 kb[64*136];   // kd; later St rows 64..127
  __shared__ u16 sb[64*136];   // St rows 0..63
  __shared__ u16 vb[128*72];   // Vt [j][s]
  __shared__ u16 pb[64*72];    // P  [t][s]
  const int c = blockIdx.x, qh = blockIdx.y, h = qh >> 2;
  const int tid = threadIdx.x, lane = tid & 63, w = tid >> 6;
  const int ml = lane & 15, quad = lane >> 4, q8 = quad * 8;

  #pragma unroll
  for (int it = 0; it < 4; it++){
    int u = it*256 + tid;              // 0..1023
    int t = u >> 4, p = (u & 15) * 8;
    size_t tok = (size_t)(c*CHUNK + t);
    *(uint4*)(qe + t*136 + p) = *(const uint4*)(qkv + tok*QKVN + qh*HD + p);
    *(uint4*)(kb + t*136 + p) = *(const uint4*)(qkv + tok*QKVN + 2048 + h*HD + p);
  }
  __syncthreads();

  // A phase
  bf16x8 aq[4];
  #pragma unroll
  for (int kk=0;kk<4;kk++)
    aq[kk] = *(const bf16x8*)(qe + (w*16 + ml)*136 + kk*32 + q8);
  #pragma unroll
  for (int n=0;n<4;n++){
    f32x4 pa = {0.f,0.f,0.f,0.f};
    #pragma unroll
    for (int kk=0;kk<4;kk++){
      bf16x8 bk = *(const bf16x8*)(kb + (n*16 + ml)*136 + kk*32 + q8);
      pa = __builtin_amdgcn_mfma_f32_16x16x32_bf16(aq[kk], bk, pa, 0, 0, 0);
    }
    #pragma unroll
    for (int r=0;r<4;r++){
      int ti = quad*4 + r;
      float v = (w*16 + ti >= n*16 + ml) ? pa[r] : 0.f;
      pb[(w*16 + ti)*72 + n*16 + ml] = f2bf(v);
    }
  }
  // stage Vt (128x64) + St rows 0..63
  #pragma unroll
  for (int it = 0; it < 4; it++){
    int u = it*256 + tid;              // 0..1023
    int j = u >> 3, p = (u & 7) * 8;
    *(uint4*)(vb + j*72 + p) =
        *(const uint4*)(Vt + ((size_t)(c*NKV + h)*HD + j)*CHUNK + p);
    int t2 = u >> 4, p2 = (u & 15) * 8;
    *(uint4*)(sb + t2*136 + p2) =
        *(const uint4*)(St + ((size_t)(c*NKV + h)*HD + t2)*HD + p2);
  }
  __syncthreads();   // A-phase done everywhere; pb/vb/sb ready; kb now dead

  f32x4 o[8];
  #pragma unroll
  for (int n=0;n<8;n++) o[n] = f32x4{0.f,0.f,0.f,0.f};
  // o += P @ Vt (K=64)
  bf16x8 ap[2];
  #pragma unroll
  for (int ks=0;ks<2;ks++)
    ap[ks] = *(const bf16x8*)(pb + (w*16 + ml)*72 + ks*32 + q8);
  #pragma unroll
  for (int n=0;n<8;n++)
    #pragma unroll
    for (int ks=0;ks<2;ks++){
      bf16x8 bv = *(const bf16x8*)(vb + (n*16 + ml)*72 + ks*32 + q8);
      o[n] = __builtin_amdgcn_mfma_f32_16x16x32_bf16(ap[ks], bv, o[n], 0, 0, 0);
    }
  // o += qe @ St (j tiles 0..3 from sb)
  #pragma unroll
  for (int n=0;n<4;n++)
    #pragma unroll
    for (int kk=0;kk<4;kk++){
      bf16x8 bs = *(const bf16x8*)(sb + (n*16 + ml)*136 + kk*32 + q8);
      o[n] = __builtin_amdgcn_mfma_f32_16x16x32_bf16(aq[kk], bs, o[n], 0, 0, 0);
    }
  // stage St rows 64..127 into kb
  #pragma unroll
  for (int it = 0; it < 4; it++){
    int u = it*256 + tid;
    int t2 = u >> 4, p2 = (u & 15) * 8;
    *(uint4*)(kb + t2*136 + p2) =
        *(const uint4*)(St + ((size_t)(c*NKV + h)*HD + 64 + t2)*HD + p2);
  }
  __syncthreads();
  #pragma unroll
  for (int n=0;n<4;n++)
    #pragma unroll
    for (int kk=0;kk<4;kk++){
      bf16x8 bs = *(const bf16x8*)(kb + (n*16 + ml)*136 + kk*32 + q8);
      o[4+n] = __builtin_amdgcn_mfma_f32_16x16x32_bf16(aq[kk], bs, o[4+n], 0, 0, 0);
    }

  // RMSNorm per row
  float rstd[4];
  #pragma unroll
  for (int r=0;r<4;r++){
    float s = 0.f;
    #pragma unroll
    for (int n=0;n<8;n++) s += o[n][r]*o[n][r];
    #pragma unroll
    for (int off=1; off<16; off<<=1) s += __shfl_xor(s, off);
    rstd[r] = rsqrtf(s*(1.f/128.f) + 1e-6f);
  }
  #pragma unroll
  for (int n=0;n<8;n++){
    float gwv = gw[n*16 + ml];
    #pragma unroll
    for (int r=0;r<4;r++){
      int t = w*16 + quad*4 + r;
      float val = o[n][r] * rstd[r] * gwv;
      obuf[(size_t)(c*CHUNK + t)*(NH*HD) + qh*HD + n*16 + ml] = f2bf(val);
    }
  }
}

extern "C" void kernel_launch(void* const* d_in, const int* in_sizes, int n_in,
                              void* d_out, int out_size, void* d_ws, size_t ws_size,
                              hipStream_t stream)
{
  const float* hs   = (const float*)d_in[0];
  const float* Wqkv = (const float*)d_in[1];
  const float* bqkv = (const float*)d_in[2];
  const float* w0   = (const float*)d_in[3];
  const float* w1   = (const float*)d_in[4];
  const float* b1   = (const float*)d_in[5];
  const float* gw   = (const float*)d_in[6];
  const float* Wo   = (const float*)d_in[7];
  float* out = (float*)d_out;

  char* ws = (char*)d_ws;
  size_t off = 0;
  auto alloc = [&](size_t bytes)->char*{
    char* p = ws + off; off += (bytes + 255) & ~(size_t)255; return p;
  };
  u16*   hsb   = (u16*)  alloc((size_t)T_TOK*HID*2);        // hs bf16
  u16*   Wt1   = (u16*)  alloc((size_t)QKVN*HID*2);         // Wqkv^T bf16
  u16*   Wt2   = (u16*)  alloc((size_t)HID*HID*2);          // Wo^T bf16
  u16*   qkv   = (u16*)  alloc((size_t)T_TOK*QKVN*2);       // qe | kd | v  bf16
  float* gtmp  = (float*)alloc((size_t)T_TOK*16*4);
  float* g     = (float*)alloc((size_t)T_TOK*512*4);
  float* ebuf  = (float*)alloc((size_t)NC*NKV*CHUNK*HD*4);  // e^{b}
  float* rbuf  = (float*)alloc((size_t)NC*NKV*CHUNK*HD*4);  // e^{-b}
  float* expB  = (float*)alloc((size_t)NC*NKV*HD*4);        // e^{b_63}
  u16*   Kt    = (u16*)  alloc((size_t)NC*NKV*HD*HD*2);     // bf16 [j][i]
  u16*   St    = (u16*)  alloc((size_t)NC*NKV*HD*HD*2);     // bf16 [j][i]
  u16*   Vt    = (u16*)  alloc((size_t)NC*NKV*HD*CHUNK*2);  // bf16 [j][s]
  u16*   obuf  = (u16*)  alloc((size_t)T_TOK*NH*HD*2);
  // Aliases into dead regions (no workspace growth vs r9-passing layout):
  // StP (32 MB f32) <- ebuf||rbuf: both 16 MB, 256-aligned, consecutive;
  //   dead after gemm_v4s's epilogue (scan_a runs strictly later in-stream).
  // carry (2 MB f32) <- g: dead after decay_kernel.
  float* StP   = ebuf;
  float* carry = g;

  cvt_f2b_kernel<<<dim3(T_TOK*HID/8/256), 256, 0, stream>>>(hs, hsb, T_TOK*HID/8);
  transpose_f2b<<<dim3(QKVN/32, HID/32), 256, 0, stream>>>(Wqkv, Wt1, HID, QKVN);
  transpose_f2b<<<dim3(HID/32,  HID/32), 256, 0, stream>>>(Wo,   Wt2, HID, HID);
  gk1_kernel<<<dim3(T_TOK/4), 256, 0, stream>>>(hsb, w0, gtmp);
  gk2_kernel<<<dim3(T_TOK*512/256), 256, 0, stream>>>(gtmp, w1, b1, g);
  decay_kernel<<<dim3(NC, NKV), 256, 0, stream>>>(g, ebuf, rbuf, expB);
  gemm_v4s<u16><<<dim3((T_TOK/128)*(QKVN/128)), 256, 0, stream>>>(
      hsb, Wt1, bqkv, ebuf, rbuf, qkv, T_TOK, QKVN, HID, 1);
  chunk_stats2_kernel<<<dim3(NC, NKV), 256, 0, stream>>>(qkv, expB, Kt, Vt);
  scan_a_kernel<<<dim3(NSEG*NKV*HD*HD/256), 256, 0, stream>>>(Kt, expB, StP, carry);
  scan_c_kernel<<<dim3(NSEG*NKV*HD*HD/256), 256, 0, stream>>>(StP, expB, carry, St);
  attn_fused_kernel<<<dim3(NC, NH), 256, 0, stream>>>(qkv, St, Vt, gw, obuf);
  gemm_v2<float><<<dim3((T_TOK/BM)*(HID/BN)), 512, 0, stream>>>(
      obuf, Wt2, nullptr, nullptr, nullptr, out, T_TOK, HID, HID, 0);
}

// Round 12
// 578.510 us; speedup vs baseline: 1.0934x; 1.0934x over previous
//
// GLA fused pipeline v8 — r9 base (best, 556.9us) + attn_fused: St direct-from-global, 61KB LDS, 2 blocks/CU
#include <hip/hip_runtime.h>
#include <hip/hip_bf16.h>
#include <cstdint>

typedef unsigned short u16;
typedef unsigned int u32;
typedef float f32x4 __attribute__((ext_vector_type(4)));
typedef short bf16x8 __attribute__((ext_vector_type(8)));

#define T_TOK 8192
#define HID 2048
#define NH 16
#define NKV 4
#define HD 128
#define QKVN 3072   // (16+2*4)*128
#define CHUNK 64
#define NC 128      // 8192/64

__device__ __forceinline__ float bf2f(u16 h){
  u32 u = ((u32)h) << 16;
  return __builtin_bit_cast(float, u);
}
__device__ __forceinline__ u16 f2bf(float f){
  u32 u = __builtin_bit_cast(u32, f);
  u32 r = (u + 0x7fffu + ((u >> 16) & 1u)) >> 16;
  return (u16)r;
}
__device__ __forceinline__ u32 pack2(float a, float b){
  return (u32)f2bf(a) | ((u32)f2bf(b) << 16);
}
// async global->LDS, 16B per lane. LDS dest must be wave-uniform base + lane*16.
__device__ __forceinline__ void gl2lds16(const u16* g, u16* l){
  __builtin_amdgcn_global_load_lds(
      (const __attribute__((address_space(1))) u32*)g,
      (__attribute__((address_space(3))) u32*)l, 16, 0, 0);
}

// f32 -> bf16 bulk convert (8 elems/thread)
__global__ __launch_bounds__(256) void cvt_f2b_kernel(
    const float* __restrict__ in, u16* __restrict__ out, int n8)
{
  int i = blockIdx.x*256 + threadIdx.x;
  if (i >= n8) return;
  const float4* p = (const float4*)(in + (size_t)i*8);
  float4 a = p[0], b = p[1];
  uint4 pk;
  pk.x = pack2(a.x, a.y); pk.y = pack2(a.z, a.w);
  pk.z = pack2(b.x, b.y); pk.w = pack2(b.z, b.w);
  *(uint4*)(out + (size_t)i*8) = pk;
}

// ---------------------------------------------------------------------------
// gemm_v2 (r4, refcheck-passed): BM=BN=256, BK=64, 512 threads, 4 phases x
// 16 MFMA per K-tile, 128 KB LDS dbuf, counted vmcnt(2), 0-conflict swizzle,
// bn-fastest XCD chunk map. Used ONLY where grid == 256 (one exact round).
// ---------------------------------------------------------------------------
#define BM 256
#define BN 256
#define BKV2 64
#define ABUF (BM*BKV2)        // u16 elements (32 KB)
#define BBUF (BN*BKV2)        // u16 elements (32 KB)
#define BUFU (ABUF + BBUF)    // 32768 u16 = 64 KB

__device__ __forceinline__ int swz(int o){ return o ^ (((o >> 7) & 7) << 4); }

__device__ __forceinline__ void stage16(const u16* g, int ldg, u16* l, int o){
  int p = o ^ (((o >> 7) & 7) << 4);   // logical byte offset (involution)
  gl2lds16(g + (size_t)(p >> 7) * ldg + ((p >> 1) & 63), l + (o >> 1));
}

__device__ __forceinline__ void stage_half(const u16* g, int ldg, u16* lregion,
                                           int half, int tid){
  stage16(g, ldg, lregion, (half*1024 + tid)*16);
  stage16(g, ldg, lregion, (half*1024 + 512 + tid)*16);
}

template<typename YT>
__global__ __launch_bounds__(512, 2) void gemm_v2(
    const u16* __restrict__ X, const u16* __restrict__ Wt,
    const float* __restrict__ bias, const float* __restrict__ ebuf,
    const float* __restrict__ rbuf, YT* __restrict__ Y,
    int M, int N, int K, int mode)
{
  __shared__ u16 lds[2 * BUFU];        // 128 KB
  const int tid  = threadIdx.x;
  const int lane = tid & 63;
  const int wave = tid >> 6;           // 0..7
  const int wm = wave >> 2;
  const int wn = wave & 3;
  const int ml = lane & 15, quad = lane >> 4;

  const int nwg = gridDim.x;           // divisible by 8
  const int chunk = nwg >> 3;
  const int lg = (blockIdx.x & 7) * chunk + (blockIdx.x >> 3);
  const int NBt = N >> 8;              // N / 256
  const int bm0 = (lg / NBt) * BM;
  const int bn0 = (lg % NBt) * BN;

  const u16* gA = X  + (size_t)bm0 * K;
  const u16* gB = Wt + (size_t)bn0 * K;

  f32x4 acc[8][4];
  #pragma unroll
  for (int i = 0; i < 8; i++)
    #pragma unroll
    for (int j = 0; j < 4; j++) acc[i][j] = f32x4{0.f, 0.f, 0.f, 0.f};

  const int NT = K >> 6;               // K / BKV2

  auto ldfrag = [&](const u16* base, int row, int kk)->bf16x8{
    return *(const bf16x8*)((const char*)base + swz(row*128 + kk*64 + quad*16));
  };

  // ---- prologue: stage tile 0 as B0,B1,A0,A1 (8 loads/thread) ----
  {
    u16* La0 = lds;
    u16* Lb0 = lds + ABUF;
    stage_half(gB, K, Lb0, 0, tid);
    stage_half(gB, K, Lb0, 1, tid);
    stage_half(gA, K, La0, 0, tid);
    stage_half(gA, K, La0, 1, tid);
  }
  asm volatile("s_waitcnt vmcnt(2)" ::: "memory");   // B0,B1,A0 landed
  __builtin_amdgcn_s_barrier();

  // ---- main loop: 4 phases per K-tile ----
  for (int t = 0; t < NT; ++t){
    u16* La = lds + (t & 1) * BUFU;
    u16* Lb = La + ABUF;
    u16* Na = lds + ((t + 1) & 1) * BUFU;
    u16* Nb = Na + ABUF;
    const u16* ga = gA + (t + 1) * BKV2;
    const u16* gb = gB + (t + 1) * BKV2;
    const bool st = (t + 1 < NT);

    #pragma unroll
    for (int kk = 0; kk < 2; ++kk){
      bf16x8 af[4], bfr[4];
      // ---- phase (kk, rh=0) ----
      #pragma unroll
      for (int j = 0; j < 4; ++j) bfr[j] = ldfrag(Lb, wn*64 + j*16 + ml, kk);
      #pragma unroll
      for (int i = 0; i < 4; ++i) af[i] = ldfrag(La, wm*64 + i*16 + ml, kk);
      if (st){
        if (kk == 0) stage_half(gb, K, Nb, 0, tid);   // B0'
        else         stage_half(ga, K, Na, 0, tid);   // A0'
      }
      __builtin_amdgcn_sched_barrier(0);
      __builtin_amdgcn_s_barrier();
      asm volatile("s_waitcnt lgkmcnt(0)" ::: "memory");
      __builtin_amdgcn_sched_barrier(0);
      __builtin_amdgcn_s_setprio(1);
      #pragma unroll
      for (int i = 0; i < 4; ++i)
        #pragma unroll
        for (int j = 0; j < 4; ++j)
          acc[i][j] = __builtin_amdgcn_mfma_f32_16x16x32_bf16(af[i], bfr[j], acc[i][j], 0, 0, 0);
      __builtin_amdgcn_s_setprio(0);
      if (kk == 0){
        if (st) asm volatile("s_waitcnt vmcnt(2)" ::: "memory");
        else    asm volatile("s_waitcnt vmcnt(0)" ::: "memory");
      }
      __builtin_amdgcn_s_barrier();

      // ---- phase (kk, rh=1) ----
      #pragma unroll
      for (int i = 0; i < 4; ++i) af[i] = ldfrag(La, 128 + wm*64 + i*16 + ml, kk);
      if (st){
        if (kk == 0) stage_half(gb, K, Nb, 1, tid);   // B1'
        else         stage_half(ga, K, Na, 1, tid);   // A1'
      }
      __builtin_amdgcn_sched_barrier(0);
      __builtin_amdgcn_s_barrier();
      asm volatile("s_waitcnt lgkmcnt(0)" ::: "memory");
      __builtin_amdgcn_sched_barrier(0);
      __builtin_amdgcn_s_setprio(1);
      #pragma unroll
      for (int i = 0; i < 4; ++i)
        #pragma unroll
        for (int j = 0; j < 4; ++j)
          acc[4+i][j] = __builtin_amdgcn_mfma_f32_16x16x32_bf16(af[i], bfr[j], acc[4+i][j], 0, 0, 0);
      __builtin_amdgcn_s_setprio(0);
      if (kk == 1 && st)
        asm volatile("s_waitcnt vmcnt(2)" ::: "memory");
      __builtin_amdgcn_s_barrier();
    }
  }

  // ---- epilogue ----
  #pragma unroll
  for (int rh = 0; rh < 2; rh++){
    #pragma unroll
    for (int i = 0; i < 4; i++){
      int row = bm0 + rh*128 + wm*64 + i*16 + quad*4;
      #pragma unroll
      for (int j = 0; j < 4; j++){
        int col = bn0 + wn*64 + j*16 + ml;
        float bv = 0.f;
        if (mode == 1) bv = bias[col];
        #pragma unroll
        for (int rr2 = 0; rr2 < 4; rr2++){
          float v = acc[rh*4+i][j][rr2] + bv;
          if (mode == 1){
            int token = row + rr2;
            int cc = token >> 6, tt = token & 63, ii = col & 127;
            if (col < 2048){
              v = fmaxf(v, 0.f) * 0.08838834764831845f;
              v *= ebuf[(((size_t)cc*4 + (col>>9))*64 + tt)*128 + ii];
            } else if (col < 2560){
              v = fmaxf(v, 0.f);
              v *= rbuf[(((size_t)cc*4 + ((col-2048)>>7))*64 + tt)*128 + ii];
            }
          }
          if (sizeof(YT) == 2) Y[(size_t)(row+rr2)*N + col] = (YT)f2bf(v);
          else                 Y[(size_t)(row+rr2)*N + col] = (YT)v;
        }
      }
    }
  }
}

// ---------------------------------------------------------------------------
// gemm_v4s (r9): m97 128^2 + 3-buffer ring + counted vmcnt + XCD map +
// both-sides XOR swizzle (0 bank conflicts, verified r9).
// ---------------------------------------------------------------------------
template<typename YT>
__global__ __launch_bounds__(256) void gemm_v4s(
    const u16* __restrict__ X, const u16* __restrict__ Wt,
    const float* __restrict__ bias, const float* __restrict__ ebuf,
    const float* __restrict__ rbuf, YT* __restrict__ Y,
    int M, int N, int K, int mode)
{
  __shared__ u16 lds[3 * 8192];        // 48 KB
  const int tid = threadIdx.x;
  const int lane = tid & 63;
  const int wave = tid >> 6;
  const int wm = wave >> 1, wn = wave & 1;

  const int nwg = gridDim.x;           // divisible by 8
  const int chunk = nwg >> 3;
  const int lg = (blockIdx.x & 7) * chunk + (blockIdx.x >> 3);
  const int NBt = N >> 7;              // N / 128
  const int bm0 = (lg / NBt) * 128;
  const int bn0 = (lg % NBt) * 128;

  f32x4 acc[4][4];
  #pragma unroll
  for (int i=0;i<4;i++)
    #pragma unroll
    for (int j=0;j<4;j++) acc[i][j] = f32x4{0.f,0.f,0.f,0.f};

  const int row0 = tid >> 2, part8 = (tid & 3) * 8;
  const int mrow = lane & 15, q16b = (lane >> 4) << 4;   // byte col of frag
  const u16* xb = X  + (size_t)bm0 * K;
  const u16* wb = Wt + (size_t)bn0 * K;

  const int NT = K >> 5;               // K / 32 (NT >= 2)

  auto scol = [&](int rr)->int{
    return (((tid & 3) * 16) ^ (((rr >> 1) & 3) << 4)) >> 1;
  };

  #pragma unroll
  for (int tt = 0; tt < 2; ++tt){
    u16* As = lds + tt * 8192;
    u16* Bs = As + 4096;
    int k0 = tt * 32;
    #pragma unroll
    for (int j=0;j<2;j++){
      int rr = j*64 + row0;
      gl2lds16(xb + (size_t)rr*K + k0 + scol(rr), As + rr*32 + part8);
      gl2lds16(wb + (size_t)rr*K + k0 + scol(rr), Bs + rr*32 + part8);
    }
  }
  asm volatile("s_waitcnt vmcnt(4)" ::: "memory");   // tile 0 landed
  __builtin_amdgcn_s_barrier();

  for (int t = 0; t < NT; ++t){
    u16* As = lds + (t % 3) * 8192;
    u16* Bs = As + 4096;
    if (t + 2 < NT){
      u16* Ns = lds + ((t + 2) % 3) * 8192;
      int k0 = (t + 2) * 32;
      #pragma unroll
      for (int j=0;j<2;j++){
        int rr = j*64 + row0;
        gl2lds16(xb + (size_t)rr*K + k0 + scol(rr), Ns + rr*32 + part8);
        gl2lds16(wb + (size_t)rr*K + k0 + scol(rr), Ns + 4096 + rr*32 + part8);
      }
    }
    bf16x8 af[4], bfr[4];
    #pragma unroll
    for (int i=0;i<4;i++){
      int ra = wm*64 + i*16 + mrow;
      int rb = wn*64 + i*16 + mrow;
      af[i]  = *(const bf16x8*)((const char*)As + ra*64 + (q16b ^ (((ra>>1)&3)<<4)));
      bfr[i] = *(const bf16x8*)((const char*)Bs + rb*64 + (q16b ^ (((rb>>1)&3)<<4)));
    }
    #pragma unroll
    for (int i=0;i<4;i++)
      #pragma unroll
      for (int j=0;j<4;j++)
        acc[i][j] = __builtin_amdgcn_mfma_f32_16x16x32_bf16(af[i], bfr[j], acc[i][j], 0, 0, 0);
    if (t + 2 < NT)      asm volatile("s_waitcnt vmcnt(4)" ::: "memory");
    else if (t + 1 < NT) asm volatile("s_waitcnt vmcnt(0)" ::: "memory");
    __builtin_amdgcn_s_barrier();
  }

  #pragma unroll
  for (int i=0;i<4;i++){
    int row = bm0 + wm*64 + i*16 + (lane>>4)*4;
    #pragma unroll
    for (int j=0;j<4;j++){
      int col = bn0 + wn*64 + j*16 + (lane&15);
      float bv = 0.f;
      if (mode == 1) bv = bias[col];
      #pragma unroll
      for (int rr2=0;rr2<4;rr2++){
        float v = acc[i][j][rr2] + bv;
        if (mode == 1){
          int token = row + rr2;
          int cc = token >> 6, tt = token & 63, ii = col & 127;
          if (col < 2048){
            v = fmaxf(v, 0.f) * 0.08838834764831845f;
            v *= ebuf[(((size_t)cc*4 + (col>>9))*64 + tt)*128 + ii];
          } else if (col < 2560){
            v = fmaxf(v, 0.f);
            v *= rbuf[(((size_t)cc*4 + ((col-2048)>>7))*64 + tt)*128 + ii];
          }
        }
        if (sizeof(YT) == 2) Y[(size_t)(row+rr2)*N + col] = (YT)f2bf(v);
        else                 Y[(size_t)(row+rr2)*N + col] = (YT)v;
      }
    }
  }
}

// in[R,C] (f32) -> out[C,R] (bf16), 32x32 LDS tiles
__global__ __launch_bounds__(256) void transpose_f2b(
    const float* __restrict__ in, u16* __restrict__ out, int R, int C)
{
  __shared__ float tile[32][33];
  int c0 = blockIdx.x*32, r0 = blockIdx.y*32;
  int tx = threadIdx.x & 31, ty = threadIdx.x >> 5;
  #pragma unroll
  for (int p=0;p<4;p++) tile[ty + p*8][tx] = in[(size_t)(r0 + ty + p*8)*C + c0 + tx];
  __syncthreads();
  #pragma unroll
  for (int p=0;p<4;p++) out[(size_t)(c0 + ty + p*8)*R + r0 + tx] = f2bf(tile[tx][ty + p*8]);
}

// gate low-rank stage 1: tmp[T,16] = hs[T,2048] @ w0[2048,16]; one wave per row
__global__ __launch_bounds__(256) void gk1_kernel(
    const u16* __restrict__ hsb, const float* __restrict__ w0, float* __restrict__ tmp)
{
  int row = blockIdx.x*4 + (threadIdx.x >> 6);
  int lane = threadIdx.x & 63;
  float acc[16];
  #pragma unroll
  for (int n=0;n<16;n++) acc[n]=0.f;
  for (int k = lane; k < HID; k += 64){
    float h = bf2f(hsb[(size_t)row*HID + k]);
    const float* wr = w0 + (size_t)k*16;
    #pragma unroll
    for (int q=0;q<4;q++){
      float4 wv = *(const float4*)(wr + q*4);
      acc[q*4+0] += h*wv.x; acc[q*4+1] += h*wv.y;
      acc[q*4+2] += h*wv.z; acc[q*4+3] += h*wv.w;
    }
  }
  #pragma unroll
  for (int n=0;n<16;n++){
    #pragma unroll
    for (int off=32; off>0; off>>=1)
      acc[n] += __shfl_down(acc[n], off);
  }
  if (lane == 0){
    #pragma unroll
    for (int n=0;n<16;n++) tmp[(size_t)row*16 + n] = acc[n];
  }
}

// gate stage 2: g[T,512] = logsigmoid(tmp @ w1 + b1) / 16
__global__ __launch_bounds__(256) void gk2_kernel(
    const float* __restrict__ tmp, const float* __restrict__ w1,
    const float* __restrict__ b1, float* __restrict__ g)
{
  int id = blockIdx.x*256 + threadIdx.x;
  int rrow = id >> 9, n = id & 511;
  float a = b1[n];
  #pragma unroll
  for (int k=0;k<16;k++)
    a += tmp[(size_t)rrow*16 + k] * w1[k*512 + n];
  float ls = fminf(a, 0.f) - log1pf(__expf(-fabsf(a)));
  g[id] = ls * 0.0625f;
}

// Per (c,h): cumsum gates -> ebuf=e^b, rbuf=e^-b (f32), expB=e^{b_63}
__global__ __launch_bounds__(256) void decay_kernel(
    const float* __restrict__ g, float* __restrict__ ebuf,
    float* __restrict__ rbuf, float* __restrict__ expB)
{
  __shared__ float bL[CHUNK*HD];
  const int c = blockIdx.x, h = blockIdx.y, tid = threadIdx.x;
  for (int off = tid; off < CHUNK*HD; off += 256){
    int t = off >> 7, i = off & 127;
    bL[off] = g[(size_t)(c*CHUNK + t)*512 + h*HD + i];
  }
  __syncthreads();
  if (tid < HD){
    float run = 0.f;
    for (int t=0;t<CHUNK;t++){ run += bL[t*HD + tid]; bL[t*HD + tid] = run; }
    expB[(size_t)(c*NKV + h)*HD + tid] = __expf(run);
  }
  __syncthreads();
  size_t base = (size_t)(c*NKV + h)*CHUNK*HD;
  for (int off = tid; off < CHUNK*HD; off += 256){
    float b = bL[off];
    ebuf[base + off] = __expf(b);
    rbuf[base + off] = __expf(-b);
  }
}

// Per (c,h): Kt[j][i] = expB[i] * sum_t v[t][j]*kd[t][i] (bf16),
//            Vt[j][s] = v[s][j] (bf16)
__global__ __launch_bounds__(256) void chunk_stats2_kernel(
    const u16* __restrict__ qkv, const float* __restrict__ expB,
    u16* __restrict__ Kt, u16* __restrict__ Vt)
{
  __shared__ u16 kL[CHUNK*HD];
  __shared__ u16 vL[CHUNK*HD];
  const int c = blockIdx.x, h = blockIdx.y, tid = threadIdx.x;
  #pragma unroll
  for (int it=0; it<4; it++){
    int u = it*256 + tid;              // 0..1023, one uint4 each of kL,vL
    int t = u >> 4, p = (u & 15)*8;
    size_t tok = (size_t)(c*CHUNK + t);
    *(uint4*)(kL + t*HD + p) = *(const uint4*)(qkv + tok*QKVN + 2048 + h*HD + p);
    *(uint4*)(vL + t*HD + p) = *(const uint4*)(qkv + tok*QKVN + 2560 + h*HD + p);
  }
  __syncthreads();
  // Vt emit
  {
    int j = tid >> 1, sh = (tid & 1)*32;
    u16* dst = Vt + ((size_t)(c*NKV + h)*HD + j)*CHUNK + sh;
    #pragma unroll
    for (int s2=0; s2<16; s2++){
      u32 a = (u32)vL[(sh + 2*s2)*HD + j] | ((u32)vL[(sh + 2*s2 + 1)*HD + j] << 16);
      *(u32*)(dst + 2*s2) = a;
    }
  }
  // Kt
  int jj = tid >> 1, ih = (tid & 1)*64;
  float acc[64];
  #pragma unroll
  for (int z=0;z<64;z++) acc[z]=0.f;
  for (int t=0;t<CHUNK;t++){
    float vj = bf2f(vL[t*HD + jj]);
    const u32* kp = (const u32*)(kL + t*HD + ih);
    #pragma unroll
    for (int z2=0; z2<32; z2++){
      u32 kw = kp[z2];
      acc[2*z2]   += vj * bf2f((u16)(kw & 0xffffu));
      acc[2*z2+1] += vj * bf2f((u16)(kw >> 16));
    }
  }
  u16* kout = Kt + ((size_t)(c*NKV + h)*HD + jj)*HD + ih;
  const float* eB = expB + (size_t)(c*NKV + h)*HD + ih;
  #pragma unroll
  for (int z2=0; z2<32; z2++)
    *(u32*)(kout + 2*z2) = pack2(acc[2*z2]*eB[2*z2], acc[2*z2+1]*eB[2*z2+1]);
}

// Sequential scan over chunks in transposed layout; St[c][h][j][i] bf16.
__global__ __launch_bounds__(256) void state_scan2_kernel(
    const u16* __restrict__ Kt, const float* __restrict__ expB, u16* __restrict__ St)
{
  int wid = blockIdx.x;                 // 256 blocks
  int h = wid >> 6;
  int j = (wid & 63)*2 + (threadIdx.x >> 7);
  int i = threadIdx.x & 127;
  size_t base = ((size_t)h*HD + j)*HD + i;
  float S = 0.f;
  for (int cc=0; cc<NC; cc++){
    size_t off = (size_t)cc*(NKV*HD*HD) + base;
    St[off] = f2bf(S);
    S = expB[((size_t)cc*NKV + h)*HD + i] * S + bf2f(Kt[off]);
  }
}

// Fused intra-chunk attention per (c, qh) — v8: St MFMA B-fragments read
// DIRECTLY from global (L2-resident: each (c,h) St tile = 32KB shared by 4
// qh-blocks) instead of LDS-staging (catalog common-mistake #7). Removes the
// sb buffer + the St->kb restage + one __syncthreads; LDS 80KB -> 61KB ->
// 2 blocks/CU (cross-block overlap of the serial phase chain, m114).
//   A = tril(qe @ kd^T)  [64x64]  -> P (LDS, bf16)
//   o = P @ Vt + qe @ St [64x128], RMSNorm rows, -> obuf bf16
__global__ __launch_bounds__(256) void attn_fused_kernel(
    const u16* __restrict__ qkv, const u16* __restrict__ St,
    const u16* __restrict__ Vt, const float* __restrict__ gw,
    u16* __restrict__ obuf)
{
  __shared__ u16 qe[64*136];
  __shared__ u16 kb[64*136];   // kd
  __shared__ u16 vb[128*72];   // Vt [j][s]
  __shared__ u16 pb[64*72];    // P  [t][s]
  const int c = blockIdx.x, qh = blockIdx.y, h = qh >> 2;
  const int tid = threadIdx.x, lane = tid & 63, w = tid >> 6;
  const int ml = lane & 15, quad = lane >> 4, q8 = quad * 8;

  #pragma unroll
  for (int it = 0; it < 4; it++){
    int u = it*256 + tid;              // 0..1023
    int t = u >> 4, p = (u & 15) * 8;
    size_t tok = (size_t)(c*CHUNK + t);
    *(uint4*)(qe + t*136 + p) = *(const uint4*)(qkv + tok*QKVN + qh*HD + p);
    *(uint4*)(kb + t*136 + p) = *(const uint4*)(qkv + tok*QKVN + 2048 + h*HD + p);
  }
  __syncthreads();

  // A phase
  bf16x8 aq[4];
  #pragma unroll
  for (int kk=0;kk<4;kk++)
    aq[kk] = *(const bf16x8*)(qe + (w*16 + ml)*136 + kk*32 + q8);
  #pragma unroll
  for (int n=0;n<4;n++){
    f32x4 pa = {0.f,0.f,0.f,0.f};
    #pragma unroll
    for (int kk=0;kk<4;kk++){
      bf16x8 bk = *(const bf16x8*)(kb + (n*16 + ml)*136 + kk*32 + q8);
      pa = __builtin_amdgcn_mfma_f32_16x16x32_bf16(aq[kk], bk, pa, 0, 0, 0);
    }
    #pragma unroll
    for (int r=0;r<4;r++){
      int ti = quad*4 + r;
      float v = (w*16 + ti >= n*16 + ml) ? pa[r] : 0.f;
      pb[(w*16 + ti)*72 + n*16 + ml] = f2bf(v);
    }
  }
  // stage Vt (128x64 = 1024 uint4)
  #pragma unroll
  for (int it = 0; it < 4; it++){
    int u = it*256 + tid;              // 0..1023
    int j = u >> 3, p = (u & 7) * 8;
    *(uint4*)(vb + j*72 + p) =
        *(const uint4*)(Vt + ((size_t)(c*NKV + h)*HD + j)*CHUNK + p);
  }
  __syncthreads();   // A-phase done everywhere; pb/vb ready

  f32x4 o[8];
  #pragma unroll
  for (int n=0;n<8;n++) o[n] = f32x4{0.f,0.f,0.f,0.f};
  bf16x8 ap[2];
  #pragma unroll
  for (int ks=0;ks<2;ks++)
    ap[ks] = *(const bf16x8*)(pb + (w*16 + ml)*72 + ks*32 + q8);
  const u16* stb = St + (size_t)(c*NKV + h)*HD*HD;   // [j][i] row-major, 128x128
  #pragma unroll
  for (int n=0;n<8;n++){
    // St fragments for this j-tile: 4x 16B global loads (L2-hit), issued
    // ahead of the PV MFMAs so they hide under matrix work.
    bf16x8 bs[4];
    #pragma unroll
    for (int kk=0;kk<4;kk++)
      bs[kk] = *(const bf16x8*)(stb + (size_t)(n*16 + ml)*HD + kk*32 + q8);
    // o += P @ Vt (K=64)
    #pragma unroll
    for (int ks=0;ks<2;ks++){
      bf16x8 bv = *(const bf16x8*)(vb + (n*16 + ml)*72 + ks*32 + q8);
      o[n] = __builtin_amdgcn_mfma_f32_16x16x32_bf16(ap[ks], bv, o[n], 0, 0, 0);
    }
    // o += qe @ St
    #pragma unroll
    for (int kk=0;kk<4;kk++)
      o[n] = __builtin_amdgcn_mfma_f32_16x16x32_bf16(aq[kk], bs[kk], o[n], 0, 0, 0);
  }

  // RMSNorm per row
  float rstd[4];
  #pragma unroll
  for (int r=0;r<4;r++){
    float s = 0.f;
    #pragma unroll
    for (int n=0;n<8;n++) s += o[n][r]*o[n][r];
    #pragma unroll
    for (int off=1; off<16; off<<=1) s += __shfl_xor(s, off);
    rstd[r] = rsqrtf(s*(1.f/128.f) + 1e-6f);
  }
  #pragma unroll
  for (int n=0;n<8;n++){
    float gwv = gw[n*16 + ml];
    #pragma unroll
    for (int r=0;r<4;r++){
      int t = w*16 + quad*4 + r;
      float val = o[n][r] * rstd[r] * gwv;
      obuf[(size_t)(c*CHUNK + t)*(NH*HD) + qh*HD + n*16 + ml] = f2bf(val);
    }
  }
}

extern "C" void kernel_launch(void* const* d_in, const int* in_sizes, int n_in,
                              void* d_out, int out_size, void* d_ws, size_t ws_size,
                              hipStream_t stream)
{
  const float* hs   = (const float*)d_in[0];
  const float* Wqkv = (const float*)d_in[1];
  const float* bqkv = (const float*)d_in[2];
  const float* w0   = (const float*)d_in[3];
  const float* w1   = (const float*)d_in[4];
  const float* b1   = (const float*)d_in[5];
  const float* gw   = (const float*)d_in[6];
  const float* Wo   = (const float*)d_in[7];
  float* out = (float*)d_out;

  char* ws = (char*)d_ws;
  size_t off = 0;
  auto alloc = [&](size_t bytes)->char*{
    char* p = ws + off; off += (bytes + 255) & ~(size_t)255; return p;
  };
  u16*   hsb   = (u16*)  alloc((size_t)T_TOK*HID*2);        // hs bf16
  u16*   Wt1   = (u16*)  alloc((size_t)QKVN*HID*2);         // Wqkv^T bf16
  u16*   Wt2   = (u16*)  alloc((size_t)HID*HID*2);          // Wo^T bf16
  u16*   qkv   = (u16*)  alloc((size_t)T_TOK*QKVN*2);       // qe | kd | v  bf16
  float* gtmp  = (float*)alloc((size_t)T_TOK*16*4);
  float* g     = (float*)alloc((size_t)T_TOK*512*4);
  float* ebuf  = (float*)alloc((size_t)NC*NKV*CHUNK*HD*4);  // e^{b}
  float* rbuf  = (float*)alloc((size_t)NC*NKV*CHUNK*HD*4);  // e^{-b}
  float* expB  = (float*)alloc((size_t)NC*NKV*HD*4);        // e^{b_63}
  u16*   Kt    = (u16*)  alloc((size_t)NC*NKV*HD*HD*2);     // bf16 [j][i]
  u16*   St    = (u16*)  alloc((size_t)NC*NKV*HD*HD*2);     // bf16 [j][i]
  u16*   Vt    = (u16*)  alloc((size_t)NC*NKV*HD*CHUNK*2);  // bf16 [j][s]
  u16*   obuf  = (u16*)  alloc((size_t)T_TOK*NH*HD*2);

  cvt_f2b_kernel<<<dim3(T_TOK*HID/8/256), 256, 0, stream>>>(hs, hsb, T_TOK*HID/8);
  transpose_f2b<<<dim3(QKVN/32, HID/32), 256, 0, stream>>>(Wqkv, Wt1, HID, QKVN);
  transpose_f2b<<<dim3(HID/32,  HID/32), 256, 0, stream>>>(Wo,   Wt2, HID, HID);
  gk1_kernel<<<dim3(T_TOK/4), 256, 0, stream>>>(hsb, w0, gtmp);
  gk2_kernel<<<dim3(T_TOK*512/256), 256, 0, stream>>>(gtmp, w1, b1, g);
  decay_kernel<<<dim3(NC, NKV), 256, 0, stream>>>(g, ebuf, rbuf, expB);
  gemm_v4s<u16><<<dim3((T_TOK/128)*(QKVN/128)), 256, 0, stream>>>(
      hsb, Wt1, bqkv, ebuf, rbuf, qkv, T_TOK, QKVN, HID, 1);
  chunk_stats2_kernel<<<dim3(NC, NKV), 256, 0, stream>>>(qkv, expB, Kt, Vt);
  state_scan2_kernel<<<dim3(256), 256, 0, stream>>>(Kt, expB, St);
  attn_fused_kernel<<<dim3(NC, NH), 256, 0, stream>>>(qkv, St, Vt, gw, obuf);
  gemm_v2<float><<<dim3((T_TOK/BM)*(HID/BN)), 512, 0, stream>>>(
      obuf, Wt2, nullptr, nullptr, nullptr, out, T_TOK, HID, HID, 0);
}

// Round 13
// 527.462 us; speedup vs baseline: 1.1992x; 1.0968x over previous
//
// GLA fused pipeline v9 — r9 base + chunk_stats3 (MFMA Kt via in-LDS transposes); attn reverted to r9
#include <hip/hip_runtime.h>
#include <hip/hip_bf16.h>
#include <cstdint>

typedef unsigned short u16;
typedef unsigned int u32;
typedef float f32x4 __attribute__((ext_vector_type(4)));
typedef short bf16x8 __attribute__((ext_vector_type(8)));

#define T_TOK 8192
#define HID 2048
#define NH 16
#define NKV 4
#define HD 128
#define QKVN 3072   // (16+2*4)*128
#define CHUNK 64
#define NC 128      // 8192/64

__device__ __forceinline__ float bf2f(u16 h){
  u32 u = ((u32)h) << 16;
  return __builtin_bit_cast(float, u);
}
__device__ __forceinline__ u16 f2bf(float f){
  u32 u = __builtin_bit_cast(u32, f);
  u32 r = (u + 0x7fffu + ((u >> 16) & 1u)) >> 16;
  return (u16)r;
}
__device__ __forceinline__ u32 pack2(float a, float b){
  return (u32)f2bf(a) | ((u32)f2bf(b) << 16);
}
// async global->LDS, 16B per lane. LDS dest must be wave-uniform base + lane*16.
__device__ __forceinline__ void gl2lds16(const u16* g, u16* l){
  __builtin_amdgcn_global_load_lds(
      (const __attribute__((address_space(1))) u32*)g,
      (__attribute__((address_space(3))) u32*)l, 16, 0, 0);
}

// f32 -> bf16 bulk convert (8 elems/thread)
__global__ __launch_bounds__(256) void cvt_f2b_kernel(
    const float* __restrict__ in, u16* __restrict__ out, int n8)
{
  int i = blockIdx.x*256 + threadIdx.x;
  if (i >= n8) return;
  const float4* p = (const float4*)(in + (size_t)i*8);
  float4 a = p[0], b = p[1];
  uint4 pk;
  pk.x = pack2(a.x, a.y); pk.y = pack2(a.z, a.w);
  pk.z = pack2(b.x, b.y); pk.w = pack2(b.z, b.w);
  *(uint4*)(out + (size_t)i*8) = pk;
}

// ---------------------------------------------------------------------------
// gemm_v2 (r4, refcheck-passed): BM=BN=256, BK=64, 512 threads, 4 phases x
// 16 MFMA per K-tile, 128 KB LDS dbuf, counted vmcnt(2), 0-conflict swizzle,
// bn-fastest XCD chunk map. Used ONLY where grid == 256 (one exact round).
// ---------------------------------------------------------------------------
#define BM 256
#define BN 256
#define BKV2 64
#define ABUF (BM*BKV2)        // u16 elements (32 KB)
#define BBUF (BN*BKV2)        // u16 elements (32 KB)
#define BUFU (ABUF + BBUF)    // 32768 u16 = 64 KB

__device__ __forceinline__ int swz(int o){ return o ^ (((o >> 7) & 7) << 4); }

__device__ __forceinline__ void stage16(const u16* g, int ldg, u16* l, int o){
  int p = o ^ (((o >> 7) & 7) << 4);   // logical byte offset (involution)
  gl2lds16(g + (size_t)(p >> 7) * ldg + ((p >> 1) & 63), l + (o >> 1));
}

__device__ __forceinline__ void stage_half(const u16* g, int ldg, u16* lregion,
                                           int half, int tid){
  stage16(g, ldg, lregion, (half*1024 + tid)*16);
  stage16(g, ldg, lregion, (half*1024 + 512 + tid)*16);
}

template<typename YT>
__global__ __launch_bounds__(512, 2) void gemm_v2(
    const u16* __restrict__ X, const u16* __restrict__ Wt,
    const float* __restrict__ bias, const float* __restrict__ ebuf,
    const float* __restrict__ rbuf, YT* __restrict__ Y,
    int M, int N, int K, int mode)
{
  __shared__ u16 lds[2 * BUFU];        // 128 KB
  const int tid  = threadIdx.x;
  const int lane = tid & 63;
  const int wave = tid >> 6;           // 0..7
  const int wm = wave >> 2;
  const int wn = wave & 3;
  const int ml = lane & 15, quad = lane >> 4;

  const int nwg = gridDim.x;           // divisible by 8
  const int chunk = nwg >> 3;
  const int lg = (blockIdx.x & 7) * chunk + (blockIdx.x >> 3);
  const int NBt = N >> 8;              // N / 256
  const int bm0 = (lg / NBt) * BM;
  const int bn0 = (lg % NBt) * BN;

  const u16* gA = X  + (size_t)bm0 * K;
  const u16* gB = Wt + (size_t)bn0 * K;

  f32x4 acc[8][4];
  #pragma unroll
  for (int i = 0; i < 8; i++)
    #pragma unroll
    for (int j = 0; j < 4; j++) acc[i][j] = f32x4{0.f, 0.f, 0.f, 0.f};

  const int NT = K >> 6;               // K / BKV2

  auto ldfrag = [&](const u16* base, int row, int kk)->bf16x8{
    return *(const bf16x8*)((const char*)base + swz(row*128 + kk*64 + quad*16));
  };

  // ---- prologue: stage tile 0 as B0,B1,A0,A1 (8 loads/thread) ----
  {
    u16* La0 = lds;
    u16* Lb0 = lds + ABUF;
    stage_half(gB, K, Lb0, 0, tid);
    stage_half(gB, K, Lb0, 1, tid);
    stage_half(gA, K, La0, 0, tid);
    stage_half(gA, K, La0, 1, tid);
  }
  asm volatile("s_waitcnt vmcnt(2)" ::: "memory");   // B0,B1,A0 landed
  __builtin_amdgcn_s_barrier();

  // ---- main loop: 4 phases per K-tile ----
  for (int t = 0; t < NT; ++t){
    u16* La = lds + (t & 1) * BUFU;
    u16* Lb = La + ABUF;
    u16* Na = lds + ((t + 1) & 1) * BUFU;
    u16* Nb = Na + ABUF;
    const u16* ga = gA + (t + 1) * BKV2;
    const u16* gb = gB + (t + 1) * BKV2;
    const bool st = (t + 1 < NT);

    #pragma unroll
    for (int kk = 0; kk < 2; ++kk){
      bf16x8 af[4], bfr[4];
      // ---- phase (kk, rh=0) ----
      #pragma unroll
      for (int j = 0; j < 4; ++j) bfr[j] = ldfrag(Lb, wn*64 + j*16 + ml, kk);
      #pragma unroll
      for (int i = 0; i < 4; ++i) af[i] = ldfrag(La, wm*64 + i*16 + ml, kk);
      if (st){
        if (kk == 0) stage_half(gb, K, Nb, 0, tid);   // B0'
        else         stage_half(ga, K, Na, 0, tid);   // A0'
      }
      __builtin_amdgcn_sched_barrier(0);
      __builtin_amdgcn_s_barrier();
      asm volatile("s_waitcnt lgkmcnt(0)" ::: "memory");
      __builtin_amdgcn_sched_barrier(0);
      __builtin_amdgcn_s_setprio(1);
      #pragma unroll
      for (int i = 0; i < 4; ++i)
        #pragma unroll
        for (int j = 0; j < 4; ++j)
          acc[i][j] = __builtin_amdgcn_mfma_f32_16x16x32_bf16(af[i], bfr[j], acc[i][j], 0, 0, 0);
      __builtin_amdgcn_s_setprio(0);
      if (kk == 0){
        if (st) asm volatile("s_waitcnt vmcnt(2)" ::: "memory");
        else    asm volatile("s_waitcnt vmcnt(0)" ::: "memory");
      }
      __builtin_amdgcn_s_barrier();

      // ---- phase (kk, rh=1) ----
      #pragma unroll
      for (int i = 0; i < 4; ++i) af[i] = ldfrag(La, 128 + wm*64 + i*16 + ml, kk);
      if (st){
        if (kk == 0) stage_half(gb, K, Nb, 1, tid);   // B1'
        else         stage_half(ga, K, Na, 1, tid);   // A1'
      }
      __builtin_amdgcn_sched_barrier(0);
      __builtin_amdgcn_s_barrier();
      asm volatile("s_waitcnt lgkmcnt(0)" ::: "memory");
      __builtin_amdgcn_sched_barrier(0);
      __builtin_amdgcn_s_setprio(1);
      #pragma unroll
      for (int i = 0; i < 4; ++i)
        #pragma unroll
        for (int j = 0; j < 4; ++j)
          acc[4+i][j] = __builtin_amdgcn_mfma_f32_16x16x32_bf16(af[i], bfr[j], acc[4+i][j], 0, 0, 0);
      __builtin_amdgcn_s_setprio(0);
      if (kk == 1 && st)
        asm volatile("s_waitcnt vmcnt(2)" ::: "memory");
      __builtin_amdgcn_s_barrier();
    }
  }

  // ---- epilogue ----
  #pragma unroll
  for (int rh = 0; rh < 2; rh++){
    #pragma unroll
    for (int i = 0; i < 4; i++){
      int row = bm0 + rh*128 + wm*64 + i*16 + quad*4;
      #pragma unroll
      for (int j = 0; j < 4; j++){
        int col = bn0 + wn*64 + j*16 + ml;
        float bv = 0.f;
        if (mode == 1) bv = bias[col];
        #pragma unroll
        for (int rr2 = 0; rr2 < 4; rr2++){
          float v = acc[rh*4+i][j][rr2] + bv;
          if (mode == 1){
            int token = row + rr2;
            int cc = token >> 6, tt = token & 63, ii = col & 127;
            if (col < 2048){
              v = fmaxf(v, 0.f) * 0.08838834764831845f;
              v *= ebuf[(((size_t)cc*4 + (col>>9))*64 + tt)*128 + ii];
            } else if (col < 2560){
              v = fmaxf(v, 0.f);
              v *= rbuf[(((size_t)cc*4 + ((col-2048)>>7))*64 + tt)*128 + ii];
            }
          }
          if (sizeof(YT) == 2) Y[(size_t)(row+rr2)*N + col] = (YT)f2bf(v);
          else                 Y[(size_t)(row+rr2)*N + col] = (YT)v;
        }
      }
    }
  }
}

// ---------------------------------------------------------------------------
// gemm_v4s (r9): m97 128^2 + 3-buffer ring + counted vmcnt + XCD map +
// both-sides XOR swizzle (0 bank conflicts, verified r9).
// ---------------------------------------------------------------------------
template<typename YT>
__global__ __launch_bounds__(256) void gemm_v4s(
    const u16* __restrict__ X, const u16* __restrict__ Wt,
    const float* __restrict__ bias, const float* __restrict__ ebuf,
    const float* __restrict__ rbuf, YT* __restrict__ Y,
    int M, int N, int K, int mode)
{
  __shared__ u16 lds[3 * 8192];        // 48 KB
  const int tid = threadIdx.x;
  const int lane = tid & 63;
  const int wave = tid >> 6;
  const int wm = wave >> 1, wn = wave & 1;

  const int nwg = gridDim.x;           // divisible by 8
  const int chunk = nwg >> 3;
  const int lg = (blockIdx.x & 7) * chunk + (blockIdx.x >> 3);
  const int NBt = N >> 7;              // N / 128
  const int bm0 = (lg / NBt) * 128;
  const int bn0 = (lg % NBt) * 128;

  f32x4 acc[4][4];
  #pragma unroll
  for (int i=0;i<4;i++)
    #pragma unroll
    for (int j=0;j<4;j++) acc[i][j] = f32x4{0.f,0.f,0.f,0.f};

  const int row0 = tid >> 2, part8 = (tid & 3) * 8;
  const int mrow = lane & 15, q16b = (lane >> 4) << 4;   // byte col of frag
  const u16* xb = X  + (size_t)bm0 * K;
  const u16* wb = Wt + (size_t)bn0 * K;

  const int NT = K >> 5;               // K / 32 (NT >= 2)

  auto scol = [&](int rr)->int{
    return (((tid & 3) * 16) ^ (((rr >> 1) & 3) << 4)) >> 1;
  };

  #pragma unroll
  for (int tt = 0; tt < 2; ++tt){
    u16* As = lds + tt * 8192;
    u16* Bs = As + 4096;
    int k0 = tt * 32;
    #pragma unroll
    for (int j=0;j<2;j++){
      int rr = j*64 + row0;
      gl2lds16(xb + (size_t)rr*K + k0 + scol(rr), As + rr*32 + part8);
      gl2lds16(wb + (size_t)rr*K + k0 + scol(rr), Bs + rr*32 + part8);
    }
  }
  asm volatile("s_waitcnt vmcnt(4)" ::: "memory");   // tile 0 landed
  __builtin_amdgcn_s_barrier();

  for (int t = 0; t < NT; ++t){
    u16* As = lds + (t % 3) * 8192;
    u16* Bs = As + 4096;
    if (t + 2 < NT){
      u16* Ns = lds + ((t + 2) % 3) * 8192;
      int k0 = (t + 2) * 32;
      #pragma unroll
      for (int j=0;j<2;j++){
        int rr = j*64 + row0;
        gl2lds16(xb + (size_t)rr*K + k0 + scol(rr), Ns + rr*32 + part8);
        gl2lds16(wb + (size_t)rr*K + k0 + scol(rr), Ns + 4096 + rr*32 + part8);
      }
    }
    bf16x8 af[4], bfr[4];
    #pragma unroll
    for (int i=0;i<4;i++){
      int ra = wm*64 + i*16 + mrow;
      int rb = wn*64 + i*16 + mrow;
      af[i]  = *(const bf16x8*)((const char*)As + ra*64 + (q16b ^ (((ra>>1)&3)<<4)));
      bfr[i] = *(const bf16x8*)((const char*)Bs + rb*64 + (q16b ^ (((rb>>1)&3)<<4)));
    }
    #pragma unroll
    for (int i=0;i<4;i++)
      #pragma unroll
      for (int j=0;j<4;j++)
        acc[i][j] = __builtin_amdgcn_mfma_f32_16x16x32_bf16(af[i], bfr[j], acc[i][j], 0, 0, 0);
    if (t + 2 < NT)      asm volatile("s_waitcnt vmcnt(4)" ::: "memory");
    else if (t + 1 < NT) asm volatile("s_waitcnt vmcnt(0)" ::: "memory");
    __builtin_amdgcn_s_barrier();
  }

  #pragma unroll
  for (int i=0;i<4;i++){
    int row = bm0 + wm*64 + i*16 + (lane>>4)*4;
    #pragma unroll
    for (int j=0;j<4;j++){
      int col = bn0 + wn*64 + j*16 + (lane&15);
      float bv = 0.f;
      if (mode == 1) bv = bias[col];
      #pragma unroll
      for (int rr2=0;rr2<4;rr2++){
        float v = acc[i][j][rr2] + bv;
        if (mode == 1){
          int token = row + rr2;
          int cc = token >> 6, tt = token & 63, ii = col & 127;
          if (col < 2048){
            v = fmaxf(v, 0.f) * 0.08838834764831845f;
            v *= ebuf[(((size_t)cc*4 + (col>>9))*64 + tt)*128 + ii];
          } else if (col < 2560){
            v = fmaxf(v, 0.f);
            v *= rbuf[(((size_t)cc*4 + ((col-2048)>>7))*64 + tt)*128 + ii];
          }
        }
        if (sizeof(YT) == 2) Y[(size_t)(row+rr2)*N + col] = (YT)f2bf(v);
        else                 Y[(size_t)(row+rr2)*N + col] = (YT)v;
      }
    }
  }
}

// in[R,C] (f32) -> out[C,R] (bf16), 32x32 LDS tiles
__global__ __launch_bounds__(256) void transpose_f2b(
    const float* __restrict__ in, u16* __restrict__ out, int R, int C)
{
  __shared__ float tile[32][33];
  int c0 = blockIdx.x*32, r0 = blockIdx.y*32;
  int tx = threadIdx.x & 31, ty = threadIdx.x >> 5;
  #pragma unroll
  for (int p=0;p<4;p++) tile[ty + p*8][tx] = in[(size_t)(r0 + ty + p*8)*C + c0 + tx];
  __syncthreads();
  #pragma unroll
  for (int p=0;p<4;p++) out[(size_t)(c0 + ty + p*8)*R + r0 + tx] = f2bf(tile[tx][ty + p*8]);
}

// gate low-rank stage 1: tmp[T,16] = hs[T,2048] @ w0[2048,16]; one wave per row
__global__ __launch_bounds__(256) void gk1_kernel(
    const u16* __restrict__ hsb, const float* __restrict__ w0, float* __restrict__ tmp)
{
  int row = blockIdx.x*4 + (threadIdx.x >> 6);
  int lane = threadIdx.x & 63;
  float acc[16];
  #pragma unroll
  for (int n=0;n<16;n++) acc[n]=0.f;
  for (int k = lane; k < HID; k += 64){
    float h = bf2f(hsb[(size_t)row*HID + k]);
    const float* wr = w0 + (size_t)k*16;
    #pragma unroll
    for (int q=0;q<4;q++){
      float4 wv = *(const float4*)(wr + q*4);
      acc[q*4+0] += h*wv.x; acc[q*4+1] += h*wv.y;
      acc[q*4+2] += h*wv.z; acc[q*4+3] += h*wv.w;
    }
  }
  #pragma unroll
  for (int n=0;n<16;n++){
    #pragma unroll
    for (int off=32; off>0; off>>=1)
      acc[n] += __shfl_down(acc[n], off);
  }
  if (lane == 0){
    #pragma unroll
    for (int n=0;n<16;n++) tmp[(size_t)row*16 + n] = acc[n];
  }
}

// gate stage 2: g[T,512] = logsigmoid(tmp @ w1 + b1) / 16
__global__ __launch_bounds__(256) void gk2_kernel(
    const float* __restrict__ tmp, const float* __restrict__ w1,
    const float* __restrict__ b1, float* __restrict__ g)
{
  int id = blockIdx.x*256 + threadIdx.x;
  int rrow = id >> 9, n = id & 511;
  float a = b1[n];
  #pragma unroll
  for (int k=0;k<16;k++)
    a += tmp[(size_t)rrow*16 + k] * w1[k*512 + n];
  float ls = fminf(a, 0.f) - log1pf(__expf(-fabsf(a)));
  g[id] = ls * 0.0625f;
}

// Per (c,h): cumsum gates -> ebuf=e^b, rbuf=e^-b (f32), expB=e^{b_63}
__global__ __launch_bounds__(256) void decay_kernel(
    const float* __restrict__ g, float* __restrict__ ebuf,
    float* __restrict__ rbuf, float* __restrict__ expB)
{
  __shared__ float bL[CHUNK*HD];
  const int c = blockIdx.x, h = blockIdx.y, tid = threadIdx.x;
  for (int off = tid; off < CHUNK*HD; off += 256){
    int t = off >> 7, i = off & 127;
    bL[off] = g[(size_t)(c*CHUNK + t)*512 + h*HD + i];
  }
  __syncthreads();
  if (tid < HD){
    float run = 0.f;
    for (int t=0;t<CHUNK;t++){ run += bL[t*HD + tid]; bL[t*HD + tid] = run; }
    expB[(size_t)(c*NKV + h)*HD + tid] = __expf(run);
  }
  __syncthreads();
  size_t base = (size_t)(c*NKV + h)*CHUNK*HD;
  for (int off = tid; off < CHUNK*HD; off += 256){
    float b = bL[off];
    ebuf[base + off] = __expf(b);
    rbuf[base + off] = __expf(-b);
  }
}

// ---------------------------------------------------------------------------
// chunk_stats3: Kt via MFMA (replaces the scalar 4096-FMA / 2048-ds_read loop
// of chunk_stats2; the Kt reduction is a 128x128x64 GEMM per (c,h)).
//  1. stage kL[t][i], vL[t][j] (as before).
//  2. build transposes ktL[i][t], vtL[j][t] in LDS via the pair-pack pattern
//     (same as the verified Vt emit; Vt global write reuses the same u32s).
//     72-u16 row pad = odd 16B-granule count -> conflict-free b128 reads
//     (identical to attn's vb layout).
//  3. MFMA: wave w owns j in [w*32,w*32+32); operand-1 row -> output row (j),
//     operand-2 row -> output col (i) (session convention, verified in both
//     GEMMs). Kt[j][i] = acc * expB[i].
// DS instrs/thread drop ~2048 -> ~160.
// ---------------------------------------------------------------------------
__global__ __launch_bounds__(256) void chunk_stats3_kernel(
    const u16* __restrict__ qkv, const float* __restrict__ expB,
    u16* __restrict__ Kt, u16* __restrict__ Vt)
{
  __shared__ u16 kL[CHUNK*HD];   // [t][i] 64x128
  __shared__ u16 vL[CHUNK*HD];   // [t][j] 64x128
  __shared__ u16 ktL[HD*72];     // [i][t] 128x64 (+8 pad)
  __shared__ u16 vtL[HD*72];     // [j][t]
  const int c = blockIdx.x, h = blockIdx.y, tid = threadIdx.x;
  const int lane = tid & 63, w = tid >> 6;
  const int ml = lane & 15, quad = lane >> 4;

  #pragma unroll
  for (int it=0; it<4; it++){
    int u = it*256 + tid;              // 0..1023, one uint4 each of kL,vL
    int t = u >> 4, p = (u & 15)*8;
    size_t tok = (size_t)(c*CHUNK + t);
    *(uint4*)(kL + t*HD + p) = *(const uint4*)(qkv + tok*QKVN + 2048 + h*HD + p);
    *(uint4*)(vL + t*HD + p) = *(const uint4*)(qkv + tok*QKVN + 2560 + h*HD + p);
  }
  __syncthreads();

  // transposes + Vt global emit (thread owns one column, one 32-half)
  {
    int col = tid >> 1, sh = (tid & 1)*32;
    u16* dstv = Vt + ((size_t)(c*NKV + h)*HD + col)*CHUNK + sh;
    #pragma unroll
    for (int s2=0; s2<16; s2++){
      u32 a = (u32)vL[(sh + 2*s2)*HD + col] | ((u32)vL[(sh + 2*s2 + 1)*HD + col] << 16);
      *(u32*)(vtL + col*72 + sh + 2*s2) = a;
      *(u32*)(dstv + 2*s2) = a;
      u32 b = (u32)kL[(sh + 2*s2)*HD + col] | ((u32)kL[(sh + 2*s2 + 1)*HD + col] << 16);
      *(u32*)(ktL + col*72 + sh + 2*s2) = b;
    }
  }
  __syncthreads();

  // MFMA: Kt[j][i] = sum_t vtL[j][t] * ktL[i][t]
  f32x4 acc[2][8];
  #pragma unroll
  for (int jt=0;jt<2;jt++)
    #pragma unroll
    for (int it=0;it<8;it++) acc[jt][it] = f32x4{0.f,0.f,0.f,0.f};
  bf16x8 avf[2][2];
  #pragma unroll
  for (int jt=0;jt<2;jt++)
    #pragma unroll
    for (int ks=0;ks<2;ks++)
      avf[jt][ks] = *(const bf16x8*)(vtL + (w*32 + jt*16 + ml)*72 + ks*32 + quad*8);
  #pragma unroll
  for (int it=0;it<8;it++){
    #pragma unroll
    for (int ks=0;ks<2;ks++){
      bf16x8 bk = *(const bf16x8*)(ktL + (it*16 + ml)*72 + ks*32 + quad*8);
      #pragma unroll
      for (int jt=0;jt<2;jt++)
        acc[jt][it] = __builtin_amdgcn_mfma_f32_16x16x32_bf16(avf[jt][ks], bk, acc[jt][it], 0, 0, 0);
    }
  }
  // epilogue: row j = w*32 + jt*16 + quad*4 + r, col i = it*16 + ml
  const float* eB = expB + (size_t)(c*NKV + h)*HD;
  u16* kout = Kt + (size_t)(c*NKV + h)*HD*HD;
  #pragma unroll
  for (int jt=0;jt<2;jt++){
    #pragma unroll
    for (int it=0;it<8;it++){
      int i = it*16 + ml;
      float e = eB[i];
      #pragma unroll
      for (int r=0;r<4;r++){
        int j = w*32 + jt*16 + quad*4 + r;
        kout[(size_t)j*HD + i] = f2bf(acc[jt][it][r] * e);
      }
    }
  }
}

// Sequential scan over chunks in transposed layout; St[c][h][j][i] bf16.
__global__ __launch_bounds__(256) void state_scan2_kernel(
    const u16* __restrict__ Kt, const float* __restrict__ expB, u16* __restrict__ St)
{
  int wid = blockIdx.x;                 // 256 blocks
  int h = wid >> 6;
  int j = (wid & 63)*2 + (threadIdx.x >> 7);
  int i = threadIdx.x & 127;
  size_t base = ((size_t)h*HD + j)*HD + i;
  float S = 0.f;
  for (int cc=0; cc<NC; cc++){
    size_t off = (size_t)cc*(NKV*HD*HD) + base;
    St[off] = f2bf(S);
    S = expB[((size_t)cc*NKV + h)*HD + i] * S + bf2f(Kt[off]);
  }
}

// Fused intra-chunk attention per (c, qh) — r9 version (reverted from v8):
//   A = tril(qe @ kd^T)  [64x64]  -> P (LDS, bf16)
//   o = P @ Vt + qe @ St [64x128], RMSNorm rows, -> obuf bf16
__global__ __launch_bounds__(256) void attn_fused_kernel(
    const u16* __restrict__ qkv, const u16* __restrict__ St,
    const u16* __restrict__ Vt, const float* __restrict__ gw,
    u16* __restrict__ obuf)
{
  __shared__ u16 qe[64*136];
  __shared__ u16 kb[64*136];   // kd; later St rows 64..127
  __shared__ u16 sb[64*136];   // St rows 0..63
  __shared__ u16 vb[128*72];   // Vt [j][s]
  __shared__ u16 pb[64*72];    // P  [t][s]
  const int c = blockIdx.x, qh = blockIdx.y, h = qh >> 2;
  const int tid = threadIdx.x, lane = tid & 63, w = tid >> 6;
  const int ml = lane & 15, quad = lane >> 4, q8 = quad * 8;

  #pragma unroll
  for (int it = 0; it < 4; it++){
    int u = it*256 + tid;              // 0..1023
    int t = u >> 4, p = (u & 15) * 8;
    size_t tok = (size_t)(c*CHUNK + t);
    *(uint4*)(qe + t*136 + p) = *(const uint4*)(qkv + tok*QKVN + qh*HD + p);
    *(uint4*)(kb + t*136 + p) = *(const uint4*)(qkv + tok*QKVN + 2048 + h*HD + p);
  }
  __syncthreads();

  // A phase
  bf16x8 aq[4];
  #pragma unroll
  for (int kk=0;kk<4;kk++)
    aq[kk] = *(const bf16x8*)(qe + (w*16 + ml)*136 + kk*32 + q8);
  #pragma unroll
  for (int n=0;n<4;n++){
    f32x4 pa = {0.f,0.f,0.f,0.f};
    #pragma unroll
    for (int kk=0;kk<4;kk++){
      bf16x8 bk = *(const bf16x8*)(kb + (n*16 + ml)*136 + kk*32 + q8);
      pa = __builtin_amdgcn_mfma_f32_16x16x32_bf16(aq[kk], bk, pa, 0, 0, 0);
    }
    #pragma unroll
    for (int r=0;r<4;r++){
      int ti = quad*4 + r;
      float v = (w*16 + ti >= n*16 + ml) ? pa[r] : 0.f;
      pb[(w*16 + ti)*72 + n*16 + ml] = f2bf(v);
    }
  }
  // stage Vt (128x64) + St rows 0..63
  #pragma unroll
  for (int it = 0; it < 4; it++){
    int u = it*256 + tid;              // 0..1023
    int j = u >> 3, p = (u & 7) * 8;
    *(uint4*)(vb + j*72 + p) =
        *(const uint4*)(Vt + ((size_t)(c*NKV + h)*HD + j)*CHUNK + p);
    int t2 = u >> 4, p2 = (u & 15) * 8;
    *(uint4*)(sb + t2*136 + p2) =
        *(const uint4*)(St + ((size_t)(c*NKV + h)*HD + t2)*HD + p2);
  }
  __syncthreads();   // A-phase done everywhere; pb/vb/sb ready; kb now dead

  f32x4 o[8];
  #pragma unroll
  for (int n=0;n<8;n++) o[n] = f32x4{0.f,0.f,0.f,0.f};
  // o += P @ Vt (K=64)
  bf16x8 ap[2];
  #pragma unroll
  for (int ks=0;ks<2;ks++)
    ap[ks] = *(const bf16x8*)(pb + (w*16 + ml)*72 + ks*32 + q8);
  #pragma unroll
  for (int n=0;n<8;n++)
    #pragma unroll
    for (int ks=0;ks<2;ks++){
      bf16x8 bv = *(const bf16x8*)(vb + (n*16 + ml)*72 + ks*32 + q8);
      o[n] = __builtin_amdgcn_mfma_f32_16x16x32_bf16(ap[ks], bv, o[n], 0, 0, 0);
    }
  // o += qe @ St (j tiles 0..3 from sb)
  #pragma unroll
  for (int n=0;n<4;n++)
    #pragma unroll
    for (int kk=0;kk<4;kk++){
      bf16x8 bs = *(const bf16x8*)(sb + (n*16 + ml)*136 + kk*32 + q8);
      o[n] = __builtin_amdgcn_mfma_f32_16x16x32_bf16(aq[kk], bs, o[n], 0, 0, 0);
    }
  // stage St rows 64..127 into kb
  #pragma unroll
  for (int it = 0; it < 4; it++){
    int u = it*256 + tid;
    int t2 = u >> 4, p2 = (u & 15) * 8;
    *(uint4*)(kb + t2*136 + p2) =
        *(const uint4*)(St + ((size_t)(c*NKV + h)*HD + 64 + t2)*HD + p2);
  }
  __syncthreads();
  #pragma unroll
  for (int n=0;n<4;n++)
    #pragma unroll
    for (int kk=0;kk<4;kk++){
      bf16x8 bs = *(const bf16x8*)(kb + (n*16 + ml)*136 + kk*32 + q8);
      o[4+n] = __builtin_amdgcn_mfma_f32_16x16x32_bf16(aq[kk], bs, o[4+n], 0, 0, 0);
    }

  // RMSNorm per row
  float rstd[4];
  #pragma unroll
  for (int r=0;r<4;r++){
    float s = 0.f;
    #pragma unroll
    for (int n=0;n<8;n++) s += o[n][r]*o[n][r];
    #pragma unroll
    for (int off=1; off<16; off<<=1) s += __shfl_xor(s, off);
    rstd[r] = rsqrtf(s*(1.f/128.f) + 1e-6f);
  }
  #pragma unroll
  for (int n=0;n<8;n++){
    float gwv = gw[n*16 + ml];
    #pragma unroll
    for (int r=0;r<4;r++){
      int t = w*16 + quad*4 + r;
      float val = o[n][r] * rstd[r] * gwv;
      obuf[(size_t)(c*CHUNK + t)*(NH*HD) + qh*HD + n*16 + ml] = f2bf(val);
    }
  }
}

extern "C" void kernel_launch(void* const* d_in, const int* in_sizes, int n_in,
                              void* d_out, int out_size, void* d_ws, size_t ws_size,
                              hipStream_t stream)
{
  const float* hs   = (const float*)d_in[0];
  const float* Wqkv = (const float*)d_in[1];
  const float* bqkv = (const float*)d_in[2];
  const float* w0   = (const float*)d_in[3];
  const float* w1   = (const float*)d_in[4];
  const float* b1   = (const float*)d_in[5];
  const float* gw   = (const float*)d_in[6];
  const float* Wo   = (const float*)d_in[7];
  float* out = (float*)d_out;

  char* ws = (char*)d_ws;
  size_t off = 0;
  auto alloc = [&](size_t bytes)->char*{
    char* p = ws + off; off += (bytes + 255) & ~(size_t)255; return p;
  };
  u16*   hsb   = (u16*)  alloc((size_t)T_TOK*HID*2);        // hs bf16
  u16*   Wt1   = (u16*)  alloc((size_t)QKVN*HID*2);         // Wqkv^T bf16
  u16*   Wt2   = (u16*)  alloc((size_t)HID*HID*2);          // Wo^T bf16
  u16*   qkv   = (u16*)  alloc((size_t)T_TOK*QKVN*2);       // qe | kd | v  bf16
  float* gtmp  = (float*)alloc((size_t)T_TOK*16*4);
  float* g     = (float*)alloc((size_t)T_TOK*512*4);
  float* ebuf  = (float*)alloc((size_t)NC*NKV*CHUNK*HD*4);  // e^{b}
  float* rbuf  = (float*)alloc((size_t)NC*NKV*CHUNK*HD*4);  // e^{-b}
  float* expB  = (float*)alloc((size_t)NC*NKV*HD*4);        // e^{b_63}
  u16*   Kt    = (u16*)  alloc((size_t)NC*NKV*HD*HD*2);     // bf16 [j][i]
  u16*   St    = (u16*)  alloc((size_t)NC*NKV*HD*HD*2);     // bf16 [j][i]
  u16*   Vt    = (u16*)  alloc((size_t)NC*NKV*HD*CHUNK*2);  // bf16 [j][s]
  u16*   obuf  = (u16*)  alloc((size_t)T_TOK*NH*HD*2);

  cvt_f2b_kernel<<<dim3(T_TOK*HID/8/256), 256, 0, stream>>>(hs, hsb, T_TOK*HID/8);
  transpose_f2b<<<dim3(QKVN/32, HID/32), 256, 0, stream>>>(Wqkv, Wt1, HID, QKVN);
  transpose_f2b<<<dim3(HID/32,  HID/32), 256, 0, stream>>>(Wo,   Wt2, HID, HID);
  gk1_kernel<<<dim3(T_TOK/4), 256, 0, stream>>>(hsb, w0, gtmp);
  gk2_kernel<<<dim3(T_TOK*512/256), 256, 0, stream>>>(gtmp, w1, b1, g);
  decay_kernel<<<dim3(NC, NKV), 256, 0, stream>>>(g, ebuf, rbuf, expB);
  gemm_v4s<u16><<<dim3((T_TOK/128)*(QKVN/128)), 256, 0, stream>>>(
      hsb, Wt1, bqkv, ebuf, rbuf, qkv, T_TOK, QKVN, HID, 1);
  chunk_stats3_kernel<<<dim3(NC, NKV), 256, 0, stream>>>(qkv, expB, Kt, Vt);
  state_scan2_kernel<<<dim3(256), 256, 0, stream>>>(Kt, expB, St);
  attn_fused_kernel<<<dim3(NC, NH), 256, 0, stream>>>(qkv, St, Vt, gw, obuf);
  gemm_v2<float><<<dim3((T_TOK/BM)*(HID/BN)), 512, 0, stream>>>(
      obuf, Wt2, nullptr, nullptr, nullptr, out, T_TOK, HID, HID, 0);
}